// Round 7
// baseline (284.668 us; speedup 1.0000x reference)
//
#include <hip/hip_runtime.h>
#include <hip/hip_bf16.h>
#include <math.h>

#define BB 32
#define SS 2048
#define HE 1024
#define HD 1024
#define WROW (HE + HD)   // 2048

typedef __attribute__((ext_vector_type(8))) short bf16x8;
typedef __attribute__((ext_vector_type(4))) float f32x4;
typedef __attribute__((ext_vector_type(16))) float f32x16;
typedef __attribute__((ext_vector_type(8))) unsigned short u16x8;

__device__ __forceinline__ unsigned short f2bf(float f) {
    union { float f; unsigned u; } v; v.f = f;
    unsigned r = v.u + 0x7fffu + ((v.u >> 16) & 1u);   // RNE
    return (unsigned short)(r >> 16);
}

__device__ __forceinline__ unsigned int pk2(float x, float y) {
    union { __hip_bfloat162 h; unsigned int u; } c;
    c.h = __float22bfloat162_rn(float2{x, y});          // v_cvt_pk_bf16_f32
    return c.u;
}

#define LGKM0()  asm volatile("s_waitcnt lgkmcnt(0)" ::: "memory")
#define BAR()    asm volatile("s_barrier" ::: "memory")

// ---------------- cvt: W_enc fp32 -> bf16 fragment-major (32x32x16 records) ----
// Record (g, ks): 64 lanes x 16B; lane l = W[d=g*32+(l&31)][k=ks*16+(l>>5)*8 ..+8]
__global__ __launch_bounds__(256) void k_cvt_wfrag(const float* __restrict__ W,
                                                   unsigned short* __restrict__ wf) {
    int i = blockIdx.x * 256 + threadIdx.x;   // 0..131071 (8-elem chunks)
    int d = i >> 7;                            // 0..1023
    int c = i & 127;                           // k-chunk: k = c*8
    const float4* src = (const float4*)(W + (size_t)d * WROW + c * 8);
    float4 a = src[0], b2 = src[1];
    u16x8 o;
    o[0] = f2bf(a.x);  o[1] = f2bf(a.y);  o[2] = f2bf(a.z);  o[3] = f2bf(a.w);
    o[4] = f2bf(b2.x); o[5] = f2bf(b2.y); o[6] = f2bf(b2.z); o[7] = f2bf(b2.w);
    int ks = c >> 1;                           // k>>4
    int l  = (d & 31) + 32 * (c & 1);          // (l>>5) = k-half
    int g  = d >> 5;
    *(u16x8*)(wf + ((size_t)(g * 64 + ks) * 64 + l) * 8) = o;
}

// ---------------- proj_dec: W_dec read ONCE total ----------------
__global__ __launch_bounds__(256) void k_projdec2(const float* __restrict__ dec,
                                                  const float* __restrict__ W,
                                                  float* __restrict__ proj) {
    const int tid = threadIdx.x;
    const int dl = tid >> 6;
    const int b  = (tid >> 1) & 31;
    const int hf = tid & 1;
    const int d  = blockIdx.x * 4 + dl;
    const float* wrow = W + (size_t)d * WROW + HE + hf * 512;
    const float* dv   = dec + b * HD + hf * 512;
    float s = 0.f;
    #pragma unroll 4
    for (int e = 0; e < 512; e += 4) {
        float4 w4 = *(const float4*)(wrow + e);
        float4 x4 = *(const float4*)(dv + e);
        s += w4.x * x4.x + w4.y * x4.y + w4.z * x4.z + w4.w * x4.w;
    }
    s += __shfl_xor(s, 1, 64);
    if (hf == 0) proj[b * HD + d] = s;
}

// ---------------- mask compaction: per-batch list of UNMASKED tokens ----------
__global__ __launch_bounds__(64) void k_compact(const int* __restrict__ mask,
                                                int* __restrict__ idx,
                                                int* __restrict__ cntblk) {
    const int b = blockIdx.x, ln = threadIdx.x;   // 32 blocks x 64 lanes
    int running = 0;
    for (int s0 = 0; s0 < SS; s0 += 64) {
        int m = mask[b * SS + s0 + ln];
        unsigned long long bal = __ballot(m == 0);
        int pos = __popcll(bal & ((1ull << ln) - 1ull));
        if (m == 0) idx[b * SS + running + pos] = s0 + ln;
        running += __popcll(bal);
    }
    int padded = (running + 63) & ~63;
    for (int i = running + ln; i < padded; i += 64) idx[b * SS + i] = (int)0x80000000;
    if (ln == 0) cntblk[b] = padded >> 6;          // chunks (<=32)
}

// ---------------- 8-wave 64x1024 scores + fused softmax-exp + PV partials ----
// R7: R6 core (compacted 64 tokens x full d, 32x32x16 MFMA) + fused epilogue:
//   p = exp(score)  (no max pass: |score| <= sum|V| <= 51 -> exp fits fp32;
//   softmax is shift-invariant so this is exact math), partial Z, and partial
//   ctx numerator N[e] = sum_s p_s * enc[s][e] (64 coalesced L2-warm row
//   reads the block just touched). Eliminates k_ctx_part's 128MB HBM re-read,
//   k_softmax's tree reductions, and k_blocktab (chunk->batch derived from
//   cntblk prefix in-kernel).
__global__ __launch_bounds__(512, 2) void k_scores_mfma8b(
        const float* __restrict__ enc,             // [65536][1024] fp32
        const unsigned short* __restrict__ wf,     // fragment-major bf16 W_enc
        const float* __restrict__ V,
        const float* __restrict__ proj,            // [32][1024]
        const int* __restrict__ idx,               // [32][2048] compacted tokens
        const int* __restrict__ cntblk,            // [32] chunk counts
        float* __restrict__ psc,                   // [65536] p = exp(score)
        float* __restrict__ pZ,                    // [32][32] partial Z
        float* __restrict__ pnum) {                // [32][32][1024] partial ctx num
    __shared__ unsigned short SM[8192];            // 16 KB: A dbuf [2][4096]

    // XCD swizzle keeps contiguous chunk ranges (~same batch) per XCD
    const int lid = (blockIdx.x & 7) * 128 + (blockIdx.x >> 3);
    int b = -1, loc = 0;
    {
        int a = 0;
        #pragma unroll
        for (int i = 0; i < 32; i++) {
            int c = cntblk[i];
            if (lid >= a && lid < a + c) { b = i; loc = lid - a; }
            a += c;
        }
    }
    if (b < 0) return;
    const int lt0 = loc << 6;

    const int tid = threadIdx.x;
    const int wv = tid >> 6, ln = tid & 63, l31 = ln & 31, hi = ln >> 5;

    // per-thread A row (K-invariant): gather via compact index
    const int rid = idx[b * SS + lt0 + (tid >> 3)];
    const size_t arow = ((size_t)b * SS + (rid & 0xffff)) * 1024;

    f32x16 acc[2][4];
    #pragma unroll
    for (int m = 0; m < 2; m++)
        #pragma unroll
        for (int n = 0; n < 4; n++)
            #pragma unroll
            for (int r = 0; r < 16; r++) acc[m][n][r] = 0.f;

    float4 areg[2];            // one K-tile of A: 64 rows x 64 k fp32, 8 fp32/thread
    bf16x8 bgE[8], bgF[8];     // B frags: [kk*4+n], E = ks 0,1  F = ks 2,3

    #define LOAD_A(k) do { \
        const float4* g_ = (const float4*)(enc + arow + (k) + (tid & 7) * 8); \
        areg[0] = g_[0]; areg[1] = g_[1]; \
    } while (0)

    #define CVTW_A(buf) do { \
        int row_ = tid >> 3; \
        union { u16x8 s; uint4 u; } pk_; \
        pk_.u.x = pk2(areg[0].x, areg[0].y); \
        pk_.u.y = pk2(areg[0].z, areg[0].w); \
        pk_.u.z = pk2(areg[1].x, areg[1].y); \
        pk_.u.w = pk2(areg[1].z, areg[1].w); \
        *(u16x8*)&SM[(buf) * 4096 + row_ * 64 + (((tid & 7) ^ (row_ & 7)) << 3)] = pk_.s; \
    } while (0)

    // B record: (g = wv*4 + n)*64 + t*4 + ksabs, lane ln
    #define LOADB(bgx, tt, ksb) do { \
        _Pragma("unroll") \
        for (int kk = 0; kk < 2; kk++) \
            _Pragma("unroll") \
            for (int n = 0; n < 4; n++) \
                bgx[kk * 4 + n] = *(const bf16x8*)(wf + ((size_t)((wv * 4 + n) * 64 + (tt) * 4 + (ksb) + kk) * 64 + ln) * 8); \
        } while (0)

    // one half-K-step (2 ks) of the wave-tile: 4 ds_reads + 16 MFMA
    #define HALF(bg, ksb, Ac) do { \
        _Pragma("unroll") \
        for (int kk = 0; kk < 2; kk++) { \
            bf16x8 af0, af1; \
            { int c_ = ((ksb) + kk) * 2 + hi; int row_ = l31; \
              af0 = *(const bf16x8*)&(Ac)[row_ * 64 + ((c_ ^ (row_ & 7)) << 3)]; } \
            { int c_ = ((ksb) + kk) * 2 + hi; int row_ = 32 + l31; \
              af1 = *(const bf16x8*)&(Ac)[row_ * 64 + ((c_ ^ (row_ & 7)) << 3)]; } \
            __builtin_amdgcn_s_setprio(1); \
            _Pragma("unroll") \
            for (int n = 0; n < 4; n++) \
                acc[0][n] = __builtin_amdgcn_mfma_f32_32x32x16_bf16(af0, bg[kk * 4 + n], acc[0][n], 0, 0, 0); \
            _Pragma("unroll") \
            for (int n = 0; n < 4; n++) \
                acc[1][n] = __builtin_amdgcn_mfma_f32_32x32x16_bf16(af1, bg[kk * 4 + n], acc[1][n], 0, 0, 0); \
            __builtin_amdgcn_s_setprio(0); \
        } } while (0)

    // ---- prologue: bg(0) both halves, A(0)->LDS, A(1) in flight ----
    LOADB(bgE, 0, 0); LOADB(bgF, 0, 2);
    LOAD_A(0);
    CVTW_A(0);                 // compiler waits A(0) loads, leaves bg in flight
    LOAD_A(64);                // A(1)
    LGKM0(); BAR();

    for (int t = 0; t < 16; ++t) {
        const int cur = t & 1, nxt = cur ^ 1;
        const unsigned short* Ac = SM + cur * 4096;

        // ks 0,1
        HALF(bgE, 0, Ac);

        // slot: bgE dead -> reload for t+1; convert A(t+1)->LDS nxt; issue A(t+2)
        if (t < 15) {
            LOADB(bgE, t + 1, 0);
            CVTW_A(nxt);                       // counted vmcnt on areg only
            if (t < 14) LOAD_A((t + 2) * 64);
        }

        // ks 2,3
        HALF(bgF, 2, Ac);

        if (t < 15) {
            LOADB(bgF, t + 1, 2);
            LGKM0(); BAR();                    // A dbuf coherence; B stays in flight
        }
    }
    #undef LOAD_A
    #undef CVTW_A
    #undef LOADB
    #undef HALF

    // ---- fused epilogue: sc[m][r] = sum_n V[d]*tanh(acc + proj) ----
    float sc[2][16];
    #pragma unroll
    for (int m = 0; m < 2; m++)
        #pragma unroll
        for (int r = 0; r < 16; r++) sc[m][r] = 0.f;
    #pragma unroll
    for (int n = 0; n < 4; n++) {
        int d = wv * 128 + n * 32 + l31;
        float pd  = proj[b * 1024 + d];
        float vv  = V[d];
        float vv2 = 2.f * vv;
        #pragma unroll
        for (int m = 0; m < 2; m++)
            #pragma unroll
            for (int r = 0; r < 16; r++) {
                float y  = acc[m][n][r] + pd;
                float e2 = __expf(2.f * y);                 // saturates at +/-inf
                float rc = __builtin_amdgcn_rcpf(e2 + 1.f);
                sc[m][r] += vv - vv2 * rc;                  // vv * tanh(y)
            }
    }

    // butterfly sum over the 32-lane column group (halves independent)
    #pragma unroll
    for (int m = 0; m < 2; m++)
        #pragma unroll
        for (int r = 0; r < 16; r++) {
            float v = sc[m][r];
            v += __shfl_xor(v, 1, 64);
            v += __shfl_xor(v, 2, 64);
            v += __shfl_xor(v, 4, 64);
            v += __shfl_xor(v, 8, 64);
            v += __shfl_xor(v, 16, 64);
            sc[m][r] = v;
        }

    __syncthreads();           // all waves done with LDS; safe to alias
    float* redf = (float*)SM;                  // [64 tok][8 wv] f32 = 2KB (off 0)
    float* pf   = (float*)SM + 512;            // p per slot, 64 f32 (off 2KB)
    int*   ri   = (int*)SM + 576;              // row id per slot, 64 ints
    if (l31 == 0) {
        #pragma unroll
        for (int m = 0; m < 2; m++)
            #pragma unroll
            for (int r = 0; r < 16; r++) {
                int tok = m * 32 + (r & 3) + 8 * (r >> 2) + 4 * hi;
                redf[tok * 8 + wv] = sc[m][r];
            }
    }
    __syncthreads();
    if (tid < 64) {
        float s = 0.f;
        #pragma unroll
        for (int w = 0; w < 8; w++) s += redf[tid * 8 + w];
        int sidx = idx[b * SS + lt0 + tid];
        float p = (sidx >= 0) ? __expf(s) : 0.f;   // shift-free softmax: |s|<=51
        if (sidx >= 0) psc[b * SS + sidx] = p;
        pf[tid] = p;
        ri[tid] = sidx & 0xffff;
        float z = p;
        z += __shfl_xor(z, 1, 64);
        z += __shfl_xor(z, 2, 64);
        z += __shfl_xor(z, 4, 64);
        z += __shfl_xor(z, 8, 64);
        z += __shfl_xor(z, 16, 64);
        z += __shfl_xor(z, 32, 64);
        if (tid == 0) pZ[b * 32 + loc] = z;
    }
    __syncthreads();

    // ---- fused PV: N[e] = sum_s p_s * enc[row_s][e] (coalesced, L2-warm) ----
    float n0 = 0.f, n1 = 0.f;
    const float* encb = enc + (size_t)b * SS * 1024;
    for (int s2 = 0; s2 < 64; s2++) {
        float p = pf[s2];
        if (p != 0.f) {                        // sentinel slots: p == 0 exactly
            const float* rp = encb + (size_t)ri[s2] * 1024;
            n0 = fmaf(p, rp[tid], n0);
            n1 = fmaf(p, rp[tid + 512], n1);
        }
    }
    float* pn = pnum + ((size_t)(b * 32 + loc)) * 1024;
    pn[tid]       = n0;
    pn[tid + 512] = n1;
}

// ---------------- attn normalize: attn = mask ? 0 : p/Z ----------------
__global__ __launch_bounds__(256) void k_norm(const float* __restrict__ psc,
                                              const int* __restrict__ mask,
                                              const float* __restrict__ pZ,
                                              const int* __restrict__ cntblk,
                                              float* __restrict__ attn) {
    const int b = blockIdx.x, tid = threadIdx.x;
    const int c = cntblk[b];
    float Z = 0.f;
    for (int q = 0; q < c; q++) Z += pZ[b * 32 + q];
    float invZ = 1.f / Z;
    #pragma unroll
    for (int i = 0; i < 8; i++) {
        int s = tid + i * 256;
        int m = mask[b * SS + s];
        float p = m ? 0.f : psc[b * SS + s];
        attn[b * SS + s] = p * invZ;
    }
}

// ---------------- ctx finalize: ctx = (sum partial N) / Z ----------------
__global__ __launch_bounds__(256) void k_ctx_final(const float* __restrict__ pnum,
                                                   const float* __restrict__ pZ,
                                                   const int* __restrict__ cntblk,
                                                   float* __restrict__ ctx) {
    int i = blockIdx.x * 256 + threadIdx.x;   // 0..32767
    int b = i >> 10, e = i & 1023;
    const int c = cntblk[b];
    float Z = 0.f;
    for (int q = 0; q < c; q++) Z += pZ[b * 32 + q];
    float s = 0.f;
    for (int q = 0; q < c; q++) s += pnum[(size_t)(b * 32 + q) * 1024 + e];
    ctx[i] = s / Z;
}

// ================= fp32 fallback (round-0 proven path) =================
__global__ __launch_bounds__(256) void k_scores_f32(const float* __restrict__ enc,
                                                    const float* __restrict__ W,
                                                    const float* __restrict__ V,
                                                    const float* __restrict__ proj,
                                                    float* __restrict__ scores) {
    __shared__ float As[64][20];
    __shared__ float Bs[64][20];
    __shared__ float red[64][17];
    const int t0 = blockIdx.x * 64;
    const int b  = t0 >> 11;
    const int tid = threadIdx.x;
    const int tx = tid & 15, ty = tid >> 4;
    const int lrow = tid >> 2, lc4 = (tid & 3) * 4;
    float sc[4] = {0.f, 0.f, 0.f, 0.f};
    for (int n0 = 0; n0 < HD; n0 += 64) {
        float C[4][4] = {};
        for (int k0 = 0; k0 < HE; k0 += 16) {
            *(float4*)&As[lrow][lc4] = *(const float4*)(enc + (size_t)(t0 + lrow) * HE + k0 + lc4);
            *(float4*)&Bs[lrow][lc4] = *(const float4*)(W + (size_t)(n0 + lrow) * WROW + k0 + lc4);
            __syncthreads();
            #pragma unroll
            for (int k4 = 0; k4 < 16; k4 += 4) {
                float4 a[4], bb[4];
                #pragma unroll
                for (int i = 0; i < 4; i++) a[i]  = *(float4*)&As[ty * 4 + i][k4];
                #pragma unroll
                for (int j = 0; j < 4; j++) bb[j] = *(float4*)&Bs[tx * 4 + j][k4];
                #pragma unroll
                for (int i = 0; i < 4; i++)
                    #pragma unroll
                    for (int j = 0; j < 4; j++)
                        C[i][j] += a[i].x * bb[j].x + a[i].y * bb[j].y +
                                   a[i].z * bb[j].z + a[i].w * bb[j].w;
            }
            __syncthreads();
        }
        #pragma unroll
        for (int j = 0; j < 4; j++) {
            int d = n0 + tx * 4 + j;
            float pd = proj[b * HD + d];
            float v  = V[d];
            #pragma unroll
            for (int i = 0; i < 4; i++) {
                float y  = C[i][j] + pd;
                float e2 = __expf(2.f * y);
                sc[i] += v * (1.f - 2.f / (e2 + 1.f));
            }
        }
    }
    #pragma unroll
    for (int i = 0; i < 4; i++) red[ty * 4 + i][tx] = sc[i];
    __syncthreads();
    if (tid < 64) {
        float s = 0.f;
        #pragma unroll
        for (int x = 0; x < 16; x++) s += red[tid][x];
        scores[t0 + tid] = s;
    }
}

__global__ __launch_bounds__(256) void k_softmax_f32(float* __restrict__ sc_attn,
                                                     const int* __restrict__ mask) {
    __shared__ float sred[256];
    const int b = blockIdx.x, tid = threadIdx.x;
    float vals[8]; int msk[8];
    float lmax = -1e30f;
    #pragma unroll
    for (int i = 0; i < 8; i++) {
        int s = tid + i * 256;
        vals[i] = sc_attn[b * SS + s];
        msk[i]  = mask[b * SS + s];
        if (!msk[i]) lmax = fmaxf(lmax, vals[i]);
    }
    sred[tid] = lmax; __syncthreads();
    for (int off = 128; off > 0; off >>= 1) {
        if (tid < off) sred[tid] = fmaxf(sred[tid], sred[tid + off]);
        __syncthreads();
    }
    float m = sred[0];
    __syncthreads();
    float ex[8]; float lsum = 0.f;
    #pragma unroll
    for (int i = 0; i < 8; i++) { ex[i] = msk[i] ? 0.f : __expf(vals[i] - m); lsum += ex[i]; }
    sred[tid] = lsum; __syncthreads();
    for (int off = 128; off > 0; off >>= 1) {
        if (tid < off) sred[tid] += sred[tid + off];
        __syncthreads();
    }
    float inv = 1.f / sred[0];
    #pragma unroll
    for (int i = 0; i < 8; i++) sc_attn[b * SS + tid + i * 256] = ex[i] * inv;
}

__global__ __launch_bounds__(256) void k_ctx_atomic(const float* __restrict__ enc,
                                                    const float* __restrict__ attn,
                                                    float* __restrict__ ctx) {
    const int b = blockIdx.x;
    const int e = blockIdx.y * 256 + threadIdx.x;
    const int s0 = blockIdx.z * 256;
    float sum = 0.f;
    for (int s = s0; s < s0 + 256; s++)
        sum += attn[b * SS + s] * enc[((size_t)b * SS + s) * HE + e];
    atomicAdd(&ctx[b * HE + e], sum);
}

extern "C" void kernel_launch(void* const* d_in, const int* in_sizes, int n_in,
                              void* d_out, int out_size, void* d_ws, size_t ws_size,
                              hipStream_t stream) {
    const float* enc  = (const float*)d_in[0];
    const float* dec  = (const float*)d_in[1];
    const int*   mask = (const int*)d_in[2];
    const float* W    = (const float*)d_in[3];
    const float* V    = (const float*)d_in[4];

    float* out  = (float*)d_out;
    float* ctx  = out;               // [32][1024]
    float* attn = out + BB * HE;     // [32][2048]

    // ws layout (bytes): wf 2M | proj 128K | psc 256K | idx 256K | cnt 4K | pZ 4K | pnum 4M
    const size_t WF_OFF = 0, PROJ_OFF = 2097152, PSC_OFF = PROJ_OFF + 131072,
                 IDX_OFF = PSC_OFF + 262144, CNT_OFF = IDX_OFF + 262144,
                 PZ_OFF = CNT_OFF + 4096, PN_OFF = PZ_OFF + 4096,
                 WS_NEED = PN_OFF + 4194304;
    if (ws_size >= WS_NEED) {
        char* w = (char*)d_ws;
        unsigned short* wf = (unsigned short*)(w + WF_OFF);
        float* proj        = (float*)(w + PROJ_OFF);
        float* psc         = (float*)(w + PSC_OFF);
        int*   idx         = (int*)(w + IDX_OFF);
        int*   cntblk      = (int*)(w + CNT_OFF);
        float* pZ          = (float*)(w + PZ_OFF);
        float* pnum        = (float*)(w + PN_OFF);

        k_compact<<<BB, 64, 0, stream>>>(mask, idx, cntblk);
        k_cvt_wfrag<<<512, 256, 0, stream>>>(W, wf);
        k_projdec2<<<256, 256, 0, stream>>>(dec, W, proj);
        k_scores_mfma8b<<<1024, 512, 0, stream>>>(enc, wf, V, proj, idx, cntblk,
                                                  psc, pZ, pnum);
        k_norm<<<BB, 256, 0, stream>>>(psc, mask, pZ, cntblk, attn);
        k_ctx_final<<<128, 256, 0, stream>>>(pnum, pZ, cntblk, ctx);
    } else {
        float* proj  = ctx;
        float* score = attn;
        k_projdec2<<<256, 256, 0, stream>>>(dec, W, proj);
        k_scores_f32<<<(BB * SS) / 64, 256, 0, stream>>>(enc, W, V, proj, score);
        k_softmax_f32<<<BB, 256, 0, stream>>>(score, mask);
        hipMemsetAsync(ctx, 0, (size_t)BB * HE * sizeof(float), stream);
        k_ctx_atomic<<<dim3(BB, HE / 256, 8), 256, 0, stream>>>(enc, attn, ctx);
    }
}

// Round 8
// 231.433 us; speedup vs baseline: 1.2300x; 1.2300x over previous
//
#include <hip/hip_runtime.h>
#include <hip/hip_bf16.h>
#include <math.h>

#define BB 32
#define SS 2048
#define HE 1024
#define HD 1024
#define WROW (HE + HD)   // 2048

typedef __attribute__((ext_vector_type(8))) short bf16x8;
typedef __attribute__((ext_vector_type(4))) float f32x4;
typedef __attribute__((ext_vector_type(16))) float f32x16;
typedef __attribute__((ext_vector_type(8))) unsigned short u16x8;

__device__ __forceinline__ unsigned short f2bf(float f) {
    union { float f; unsigned u; } v; v.f = f;
    unsigned r = v.u + 0x7fffu + ((v.u >> 16) & 1u);   // RNE
    return (unsigned short)(r >> 16);
}

__device__ __forceinline__ unsigned int pk2(float x, float y) {
    union { __hip_bfloat162 h; unsigned int u; } c;
    c.h = __float22bfloat162_rn(float2{x, y});          // v_cvt_pk_bf16_f32
    return c.u;
}

#define LGKM0()  asm volatile("s_waitcnt lgkmcnt(0)" ::: "memory")
#define BAR()    asm volatile("s_barrier" ::: "memory")

// ---------------- cvt: W_enc fp32 -> bf16 fragment-major (32x32x16 records) ----
// Record (g, ks): 64 lanes x 16B; lane l = W[d=g*32+(l&31)][k=ks*16+(l>>5)*8 ..+8]
__global__ __launch_bounds__(256) void k_cvt_wfrag(const float* __restrict__ W,
                                                   unsigned short* __restrict__ wf) {
    int i = blockIdx.x * 256 + threadIdx.x;   // 0..131071 (8-elem chunks)
    int d = i >> 7;                            // 0..1023
    int c = i & 127;                           // k-chunk: k = c*8
    const float4* src = (const float4*)(W + (size_t)d * WROW + c * 8);
    float4 a = src[0], b2 = src[1];
    u16x8 o;
    o[0] = f2bf(a.x);  o[1] = f2bf(a.y);  o[2] = f2bf(a.z);  o[3] = f2bf(a.w);
    o[4] = f2bf(b2.x); o[5] = f2bf(b2.y); o[6] = f2bf(b2.z); o[7] = f2bf(b2.w);
    int ks = c >> 1;                           // k>>4
    int l  = (d & 31) + 32 * (c & 1);          // (l>>5) = k-half
    int g  = d >> 5;
    *(u16x8*)(wf + ((size_t)(g * 64 + ks) * 64 + l) * 8) = o;
}

// ---------------- proj_dec: W_dec read ONCE total ----------------
__global__ __launch_bounds__(256) void k_projdec2(const float* __restrict__ dec,
                                                  const float* __restrict__ W,
                                                  float* __restrict__ proj) {
    const int tid = threadIdx.x;
    const int dl = tid >> 6;
    const int b  = (tid >> 1) & 31;
    const int hf = tid & 1;
    const int d  = blockIdx.x * 4 + dl;
    const float* wrow = W + (size_t)d * WROW + HE + hf * 512;
    const float* dv   = dec + b * HD + hf * 512;
    float s = 0.f;
    #pragma unroll 4
    for (int e = 0; e < 512; e += 4) {
        float4 w4 = *(const float4*)(wrow + e);
        float4 x4 = *(const float4*)(dv + e);
        s += w4.x * x4.x + w4.y * x4.y + w4.z * x4.z + w4.w * x4.w;
    }
    s += __shfl_xor(s, 1, 64);
    if (hf == 0) proj[b * HD + d] = s;
}

// ---------------- mask compaction: per-batch list of UNMASKED tokens ----------
__global__ __launch_bounds__(64) void k_compact(const int* __restrict__ mask,
                                                int* __restrict__ idx,
                                                int* __restrict__ cntblk) {
    const int b = blockIdx.x, ln = threadIdx.x;   // 32 blocks x 64 lanes
    int running = 0;
    for (int s0 = 0; s0 < SS; s0 += 64) {
        int m = mask[b * SS + s0 + ln];
        unsigned long long bal = __ballot(m == 0);
        int pos = __popcll(bal & ((1ull << ln) - 1ull));
        if (m == 0) idx[b * SS + running + pos] = s0 + ln;
        running += __popcll(bal);
    }
    int padded = (running + 63) & ~63;
    for (int i = running + ln; i < padded; i += 64) idx[b * SS + i] = (int)0x80000000;
    if (ln == 0) cntblk[b] = padded >> 6;          // chunk count (<=32)
}

// ---------------- 8-wave 64x1024 scores + exp + partial Z (NO PV tail) -------
// R8: R6 core (compacted 64 tokens x full d, 32x32x16 MFMA, 2 blocks/CU) +
// R7's PROVEN cheap epilogue: p = exp(score) (shift-free: |score| <= sum|V|
// <= 51, fp32-safe; softmax shift-invariant -> exact), partial Z per chunk.
// The R7 PV tail (latency-poison at 2 blocks/CU, occupancy 22->10.8, +180us)
// is moved to k_ctx_dense at high occupancy. blocktab folded in (prefix scan
// over cntblk in-kernel, R7-proven).
__global__ __launch_bounds__(512, 2) void k_scores_mfma8b(
        const float* __restrict__ enc,             // [65536][1024] fp32
        const unsigned short* __restrict__ wf,     // fragment-major bf16 W_enc
        const float* __restrict__ V,
        const float* __restrict__ proj,            // [32][1024]
        const int* __restrict__ idx,               // [32][2048] compacted tokens
        const int* __restrict__ cntblk,            // [32] chunk counts
        float* __restrict__ psc,                   // [65536] p = exp(score)
        float* __restrict__ pZ) {                  // [32][32] partial Z
    __shared__ unsigned short SM[8192];            // 16 KB: A dbuf [2][4096]

    // XCD swizzle keeps contiguous chunk ranges (~same batch) per XCD
    const int lid = (blockIdx.x & 7) * 128 + (blockIdx.x >> 3);
    int b = -1, loc = 0;
    {
        int a = 0;
        #pragma unroll
        for (int i = 0; i < 32; i++) {
            int c = cntblk[i];
            if (lid >= a && lid < a + c) { b = i; loc = lid - a; }
            a += c;
        }
    }
    if (b < 0) return;
    const int lt0 = loc << 6;

    const int tid = threadIdx.x;
    const int wv = tid >> 6, ln = tid & 63, l31 = ln & 31, hi = ln >> 5;

    // per-thread A row (K-invariant): gather via compact index
    const int rid = idx[b * SS + lt0 + (tid >> 3)];
    const size_t arow = ((size_t)b * SS + (rid & 0xffff)) * 1024;

    f32x16 acc[2][4];
    #pragma unroll
    for (int m = 0; m < 2; m++)
        #pragma unroll
        for (int n = 0; n < 4; n++)
            #pragma unroll
            for (int r = 0; r < 16; r++) acc[m][n][r] = 0.f;

    float4 areg[2];            // one K-tile of A: 64 rows x 64 k fp32, 8 fp32/thread
    bf16x8 bgE[8], bgF[8];     // B frags: [kk*4+n], E = ks 0,1  F = ks 2,3

    #define LOAD_A(k) do { \
        const float4* g_ = (const float4*)(enc + arow + (k) + (tid & 7) * 8); \
        areg[0] = g_[0]; areg[1] = g_[1]; \
    } while (0)

    #define CVTW_A(buf) do { \
        int row_ = tid >> 3; \
        union { u16x8 s; uint4 u; } pk_; \
        pk_.u.x = pk2(areg[0].x, areg[0].y); \
        pk_.u.y = pk2(areg[0].z, areg[0].w); \
        pk_.u.z = pk2(areg[1].x, areg[1].y); \
        pk_.u.w = pk2(areg[1].z, areg[1].w); \
        *(u16x8*)&SM[(buf) * 4096 + row_ * 64 + (((tid & 7) ^ (row_ & 7)) << 3)] = pk_.s; \
    } while (0)

    // B record: (g = wv*4 + n)*64 + t*4 + ksabs, lane ln
    #define LOADB(bgx, tt, ksb) do { \
        _Pragma("unroll") \
        for (int kk = 0; kk < 2; kk++) \
            _Pragma("unroll") \
            for (int n = 0; n < 4; n++) \
                bgx[kk * 4 + n] = *(const bf16x8*)(wf + ((size_t)((wv * 4 + n) * 64 + (tt) * 4 + (ksb) + kk) * 64 + ln) * 8); \
        } while (0)

    // one half-K-step (2 ks) of the wave-tile: 4 ds_reads + 16 MFMA
    #define HALF(bg, ksb, Ac) do { \
        _Pragma("unroll") \
        for (int kk = 0; kk < 2; kk++) { \
            bf16x8 af0, af1; \
            { int c_ = ((ksb) + kk) * 2 + hi; int row_ = l31; \
              af0 = *(const bf16x8*)&(Ac)[row_ * 64 + ((c_ ^ (row_ & 7)) << 3)]; } \
            { int c_ = ((ksb) + kk) * 2 + hi; int row_ = 32 + l31; \
              af1 = *(const bf16x8*)&(Ac)[row_ * 64 + ((c_ ^ (row_ & 7)) << 3)]; } \
            __builtin_amdgcn_s_setprio(1); \
            _Pragma("unroll") \
            for (int n = 0; n < 4; n++) \
                acc[0][n] = __builtin_amdgcn_mfma_f32_32x32x16_bf16(af0, bg[kk * 4 + n], acc[0][n], 0, 0, 0); \
            _Pragma("unroll") \
            for (int n = 0; n < 4; n++) \
                acc[1][n] = __builtin_amdgcn_mfma_f32_32x32x16_bf16(af1, bg[kk * 4 + n], acc[1][n], 0, 0, 0); \
            __builtin_amdgcn_s_setprio(0); \
        } } while (0)

    // ---- prologue: bg(0) both halves, A(0)->LDS, A(1) in flight ----
    LOADB(bgE, 0, 0); LOADB(bgF, 0, 2);
    LOAD_A(0);
    CVTW_A(0);                 // compiler waits A(0) loads, leaves bg in flight
    LOAD_A(64);                // A(1)
    LGKM0(); BAR();

    for (int t = 0; t < 16; ++t) {
        const int cur = t & 1, nxt = cur ^ 1;
        const unsigned short* Ac = SM + cur * 4096;

        // ks 0,1
        HALF(bgE, 0, Ac);

        // slot: bgE dead -> reload for t+1; convert A(t+1)->LDS nxt; issue A(t+2)
        if (t < 15) {
            LOADB(bgE, t + 1, 0);
            CVTW_A(nxt);                       // counted vmcnt on areg only
            if (t < 14) LOAD_A((t + 2) * 64);
        }

        // ks 2,3
        HALF(bgF, 2, Ac);

        if (t < 15) {
            LOADB(bgF, t + 1, 2);
            LGKM0(); BAR();                    // A dbuf coherence; B stays in flight
        }
    }
    #undef LOAD_A
    #undef CVTW_A
    #undef LOADB
    #undef HALF

    // ---- fused epilogue: sc[m][r] = sum_n V[d]*tanh(acc + proj) ----
    float sc[2][16];
    #pragma unroll
    for (int m = 0; m < 2; m++)
        #pragma unroll
        for (int r = 0; r < 16; r++) sc[m][r] = 0.f;
    #pragma unroll
    for (int n = 0; n < 4; n++) {
        int d = wv * 128 + n * 32 + l31;
        float pd  = proj[b * 1024 + d];
        float vv  = V[d];
        float vv2 = 2.f * vv;
        #pragma unroll
        for (int m = 0; m < 2; m++)
            #pragma unroll
            for (int r = 0; r < 16; r++) {
                float y  = acc[m][n][r] + pd;
                float e2 = __expf(2.f * y);                 // saturates at +/-inf
                float rc = __builtin_amdgcn_rcpf(e2 + 1.f);
                sc[m][r] += vv - vv2 * rc;                  // vv * tanh(y)
            }
    }

    // butterfly sum over the 32-lane column group (halves independent)
    #pragma unroll
    for (int m = 0; m < 2; m++)
        #pragma unroll
        for (int r = 0; r < 16; r++) {
            float v = sc[m][r];
            v += __shfl_xor(v, 1, 64);
            v += __shfl_xor(v, 2, 64);
            v += __shfl_xor(v, 4, 64);
            v += __shfl_xor(v, 8, 64);
            v += __shfl_xor(v, 16, 64);
            sc[m][r] = v;
        }

    __syncthreads();           // all waves done with LDS; safe to alias
    float* redf = (float*)SM;  // [64 tokens][8 waves] f32 = 2KB
    if (l31 == 0) {
        #pragma unroll
        for (int m = 0; m < 2; m++)
            #pragma unroll
            for (int r = 0; r < 16; r++) {
                int tok = m * 32 + (r & 3) + 8 * (r >> 2) + 4 * hi;
                redf[tok * 8 + wv] = sc[m][r];
            }
    }
    __syncthreads();
    if (tid < 64) {
        float s = 0.f;
        #pragma unroll
        for (int w = 0; w < 8; w++) s += redf[tid * 8 + w];
        int sidx = idx[b * SS + lt0 + tid];
        float p = (sidx >= 0) ? __expf(s) : 0.f;   // shift-free softmax: |s|<=51
        if (sidx >= 0) psc[b * SS + sidx] = p;
        float z = p;
        z += __shfl_xor(z, 1, 64);
        z += __shfl_xor(z, 2, 64);
        z += __shfl_xor(z, 4, 64);
        z += __shfl_xor(z, 8, 64);
        z += __shfl_xor(z, 16, 64);
        z += __shfl_xor(z, 32, 64);
        if (tid == 0) pZ[b * 32 + loc] = z;
    }
}

// ---------------- attn normalize: attn = mask ? 0 : p/Z (no trees) ----------
__global__ __launch_bounds__(256) void k_norm(const float* __restrict__ psc,
                                              const int* __restrict__ mask,
                                              const float* __restrict__ pZ,
                                              const int* __restrict__ cntblk,
                                              float* __restrict__ attn) {
    const int b = blockIdx.x, tid = threadIdx.x;
    const int c = cntblk[b];
    float Z = 0.f;
    for (int q = 0; q < c; q++) Z += pZ[b * 32 + q];
    float invZ = 1.f / Z;
    #pragma unroll
    for (int i = 0; i < 8; i++) {
        int s = tid + i * 256;
        int m = mask[b * SS + s];
        float p = m ? 0.f : psc[b * SS + s];
        attn[b * SS + s] = p * invZ;
    }
}

// ---------------- ctx partials: DENSE over compacted rows, high occupancy ----
// Grid (b, chunk z<32), early-exit z >= cntblk[b]. 64 live rows per block via
// idx, branch-free (sentinel -> row 0 x p=0), unroll-4 for MLP. Small VGPR ->
// 8+ blocks/CU; the R7 lesson: PV must run at high occupancy.
__global__ __launch_bounds__(256) void k_ctx_dense(const float* __restrict__ enc,
                                                   const float* __restrict__ psc,
                                                   const int* __restrict__ idx,
                                                   const int* __restrict__ cntblk,
                                                   float* __restrict__ pctx) {
    const int b = blockIdx.x, z = blockIdx.y, tid = threadIdx.x;
    if (z >= cntblk[b]) return;
    const int*    ix = idx + b * SS + z * 64;
    const float*  pb = psc + b * SS;
    const float4* e4 = (const float4*)(enc + (size_t)b * SS * 1024);
    float4 acc = {0.f, 0.f, 0.f, 0.f};
    #pragma unroll 4
    for (int s = 0; s < 64; s++) {
        int sidx = ix[s];
        int row  = sidx & 0xffff;                    // sentinel -> row 0
        float p  = (sidx >= 0) ? pb[sidx] : 0.f;     // sentinel -> p = 0
        float4 v = e4[(size_t)row * 256 + tid];
        acc.x = fmaf(p, v.x, acc.x); acc.y = fmaf(p, v.y, acc.y);
        acc.z = fmaf(p, v.z, acc.z); acc.w = fmaf(p, v.w, acc.w);
    }
    *(float4*)(pctx + ((size_t)z * 32 + b) * 1024 + tid * 4) = acc;
}

// ---------------- ctx finalize: ctx = (sum partial N) / Z ----------------
__global__ __launch_bounds__(256) void k_ctx_final(const float* __restrict__ pctx,
                                                   const float* __restrict__ pZ,
                                                   const int* __restrict__ cntblk,
                                                   float* __restrict__ ctx) {
    int i = blockIdx.x * 256 + threadIdx.x;   // 0..32767
    int b = i >> 10, e = i & 1023;
    const int c = cntblk[b];
    float Z = 0.f;
    for (int q = 0; q < c; q++) Z += pZ[b * 32 + q];
    float s = 0.f;
    for (int q = 0; q < c; q++) s += pctx[(size_t)(q * 32 + b) * 1024 + e];
    ctx[i] = s / Z;
}

// ================= fp32 fallback (round-0 proven path) =================
__global__ __launch_bounds__(256) void k_scores_f32(const float* __restrict__ enc,
                                                    const float* __restrict__ W,
                                                    const float* __restrict__ V,
                                                    const float* __restrict__ proj,
                                                    float* __restrict__ scores) {
    __shared__ float As[64][20];
    __shared__ float Bs[64][20];
    __shared__ float red[64][17];
    const int t0 = blockIdx.x * 64;
    const int b  = t0 >> 11;
    const int tid = threadIdx.x;
    const int tx = tid & 15, ty = tid >> 4;
    const int lrow = tid >> 2, lc4 = (tid & 3) * 4;
    float sc[4] = {0.f, 0.f, 0.f, 0.f};
    for (int n0 = 0; n0 < HD; n0 += 64) {
        float C[4][4] = {};
        for (int k0 = 0; k0 < HE; k0 += 16) {
            *(float4*)&As[lrow][lc4] = *(const float4*)(enc + (size_t)(t0 + lrow) * HE + k0 + lc4);
            *(float4*)&Bs[lrow][lc4] = *(const float4*)(W + (size_t)(n0 + lrow) * WROW + k0 + lc4);
            __syncthreads();
            #pragma unroll
            for (int k4 = 0; k4 < 16; k4 += 4) {
                float4 a[4], bb[4];
                #pragma unroll
                for (int i = 0; i < 4; i++) a[i]  = *(float4*)&As[ty * 4 + i][k4];
                #pragma unroll
                for (int j = 0; j < 4; j++) bb[j] = *(float4*)&Bs[tx * 4 + j][k4];
                #pragma unroll
                for (int i = 0; i < 4; i++)
                    #pragma unroll
                    for (int j = 0; j < 4; j++)
                        C[i][j] += a[i].x * bb[j].x + a[i].y * bb[j].y +
                                   a[i].z * bb[j].z + a[i].w * bb[j].w;
            }
            __syncthreads();
        }
        #pragma unroll
        for (int j = 0; j < 4; j++) {
            int d = n0 + tx * 4 + j;
            float pd = proj[b * HD + d];
            float v  = V[d];
            #pragma unroll
            for (int i = 0; i < 4; i++) {
                float y  = C[i][j] + pd;
                float e2 = __expf(2.f * y);
                sc[i] += v * (1.f - 2.f / (e2 + 1.f));
            }
        }
    }
    #pragma unroll
    for (int i = 0; i < 4; i++) red[ty * 4 + i][tx] = sc[i];
    __syncthreads();
    if (tid < 64) {
        float s = 0.f;
        #pragma unroll
        for (int x = 0; x < 16; x++) s += red[tid][x];
        scores[t0 + tid] = s;
    }
}

__global__ __launch_bounds__(256) void k_softmax_f32(float* __restrict__ sc_attn,
                                                     const int* __restrict__ mask) {
    __shared__ float sred[256];
    const int b = blockIdx.x, tid = threadIdx.x;
    float vals[8]; int msk[8];
    float lmax = -1e30f;
    #pragma unroll
    for (int i = 0; i < 8; i++) {
        int s = tid + i * 256;
        vals[i] = sc_attn[b * SS + s];
        msk[i]  = mask[b * SS + s];
        if (!msk[i]) lmax = fmaxf(lmax, vals[i]);
    }
    sred[tid] = lmax; __syncthreads();
    for (int off = 128; off > 0; off >>= 1) {
        if (tid < off) sred[tid] = fmaxf(sred[tid], sred[tid + off]);
        __syncthreads();
    }
    float m = sred[0];
    __syncthreads();
    float ex[8]; float lsum = 0.f;
    #pragma unroll
    for (int i = 0; i < 8; i++) { ex[i] = msk[i] ? 0.f : __expf(vals[i] - m); lsum += ex[i]; }
    sred[tid] = lsum; __syncthreads();
    for (int off = 128; off > 0; off >>= 1) {
        if (tid < off) sred[tid] += sred[tid + off];
        __syncthreads();
    }
    float inv = 1.f / sred[0];
    #pragma unroll
    for (int i = 0; i < 8; i++) sc_attn[b * SS + tid + i * 256] = ex[i] * inv;
}

__global__ __launch_bounds__(256) void k_ctx_atomic(const float* __restrict__ enc,
                                                    const float* __restrict__ attn,
                                                    float* __restrict__ ctx) {
    const int b = blockIdx.x;
    const int e = blockIdx.y * 256 + threadIdx.x;
    const int s0 = blockIdx.z * 256;
    float sum = 0.f;
    for (int s = s0; s < s0 + 256; s++)
        sum += attn[b * SS + s] * enc[((size_t)b * SS + s) * HE + e];
    atomicAdd(&ctx[b * HE + e], sum);
}

extern "C" void kernel_launch(void* const* d_in, const int* in_sizes, int n_in,
                              void* d_out, int out_size, void* d_ws, size_t ws_size,
                              hipStream_t stream) {
    const float* enc  = (const float*)d_in[0];
    const float* dec  = (const float*)d_in[1];
    const int*   mask = (const int*)d_in[2];
    const float* W    = (const float*)d_in[3];
    const float* V    = (const float*)d_in[4];

    float* out  = (float*)d_out;
    float* ctx  = out;               // [32][1024]
    float* attn = out + BB * HE;     // [32][2048]

    // ws layout (bytes): wf 2M | proj 128K | psc 256K | idx 256K | cnt 4K | pZ 4K | pctx 4M
    const size_t WF_OFF = 0, PROJ_OFF = 2097152, PSC_OFF = PROJ_OFF + 131072,
                 IDX_OFF = PSC_OFF + 262144, CNT_OFF = IDX_OFF + 262144,
                 PZ_OFF = CNT_OFF + 4096, PC_OFF = PZ_OFF + 4096,
                 WS_NEED = PC_OFF + 4194304;
    if (ws_size >= WS_NEED) {
        char* w = (char*)d_ws;
        unsigned short* wf = (unsigned short*)(w + WF_OFF);
        float* proj        = (float*)(w + PROJ_OFF);
        float* psc         = (float*)(w + PSC_OFF);
        int*   idx         = (int*)(w + IDX_OFF);
        int*   cntblk      = (int*)(w + CNT_OFF);
        float* pZ          = (float*)(w + PZ_OFF);
        float* pctx        = (float*)(w + PC_OFF);

        k_compact<<<BB, 64, 0, stream>>>(mask, idx, cntblk);
        k_cvt_wfrag<<<512, 256, 0, stream>>>(W, wf);
        k_projdec2<<<256, 256, 0, stream>>>(dec, W, proj);
        k_scores_mfma8b<<<1024, 512, 0, stream>>>(enc, wf, V, proj, idx, cntblk,
                                                  psc, pZ);
        k_norm<<<BB, 256, 0, stream>>>(psc, mask, pZ, cntblk, attn);
        k_ctx_dense<<<dim3(BB, 32), 256, 0, stream>>>(enc, psc, idx, cntblk, pctx);
        k_ctx_final<<<128, 256, 0, stream>>>(pctx, pZ, cntblk, ctx);
    } else {
        float* proj  = ctx;
        float* score = attn;
        k_projdec2<<<256, 256, 0, stream>>>(dec, W, proj);
        k_scores_f32<<<(BB * SS) / 64, 256, 0, stream>>>(enc, W, V, proj, score);
        k_softmax_f32<<<BB, 256, 0, stream>>>(score, mask);
        hipMemsetAsync(ctx, 0, (size_t)BB * HE * sizeof(float), stream);
        k_ctx_atomic<<<dim3(BB, HE / 256, 8), 256, 0, stream>>>(enc, attn, ctx);
    }
}

// Round 9
// 193.212 us; speedup vs baseline: 1.4733x; 1.1978x over previous
//
#include <hip/hip_runtime.h>
#include <hip/hip_bf16.h>
#include <math.h>

#define BB 32
#define SS 2048
#define HE 1024
#define HD 1024
#define WROW (HE + HD)   // 2048

typedef __attribute__((ext_vector_type(8))) short bf16x8;
typedef __attribute__((ext_vector_type(4))) float f32x4;
typedef __attribute__((ext_vector_type(16))) float f32x16;
typedef __attribute__((ext_vector_type(8))) unsigned short u16x8;

__device__ __forceinline__ unsigned short f2bf(float f) {
    union { float f; unsigned u; } v; v.f = f;
    unsigned r = v.u + 0x7fffu + ((v.u >> 16) & 1u);   // RNE
    return (unsigned short)(r >> 16);
}

__device__ __forceinline__ unsigned int pk2(float x, float y) {
    union { __hip_bfloat162 h; unsigned int u; } c;
    c.h = __float22bfloat162_rn(float2{x, y});          // v_cvt_pk_bf16_f32
    return c.u;
}

#define LGKM0()  asm volatile("s_waitcnt lgkmcnt(0)" ::: "memory")
#define BAR()    asm volatile("s_barrier" ::: "memory")

// ---------------- cvt: W_enc fp32 -> bf16 fragment-major (32x32x16 records) ----
// Record (g, ks): 64 lanes x 16B; lane l = W[d=g*32+(l&31)][k=ks*16+(l>>5)*8 ..+8]
__global__ __launch_bounds__(256) void k_cvt_wfrag(const float* __restrict__ W,
                                                   unsigned short* __restrict__ wf) {
    int i = blockIdx.x * 256 + threadIdx.x;   // 0..131071 (8-elem chunks)
    int d = i >> 7;                            // 0..1023
    int c = i & 127;                           // k-chunk: k = c*8
    const float4* src = (const float4*)(W + (size_t)d * WROW + c * 8);
    float4 a = src[0], b2 = src[1];
    u16x8 o;
    o[0] = f2bf(a.x);  o[1] = f2bf(a.y);  o[2] = f2bf(a.z);  o[3] = f2bf(a.w);
    o[4] = f2bf(b2.x); o[5] = f2bf(b2.y); o[6] = f2bf(b2.z); o[7] = f2bf(b2.w);
    int ks = c >> 1;                           // k>>4
    int l  = (d & 31) + 32 * (c & 1);          // (l>>5) = k-half
    int g  = d >> 5;
    *(u16x8*)(wf + ((size_t)(g * 64 + ks) * 64 + l) * 8) = o;
}

// ---------------- proj_dec: W_dec read ONCE total ----------------
__global__ __launch_bounds__(256) void k_projdec2(const float* __restrict__ dec,
                                                  const float* __restrict__ W,
                                                  float* __restrict__ proj) {
    const int tid = threadIdx.x;
    const int dl = tid >> 6;
    const int b  = (tid >> 1) & 31;
    const int hf = tid & 1;
    const int d  = blockIdx.x * 4 + dl;
    const float* wrow = W + (size_t)d * WROW + HE + hf * 512;
    const float* dv   = dec + b * HD + hf * 512;
    float s = 0.f;
    #pragma unroll 4
    for (int e = 0; e < 512; e += 4) {
        float4 w4 = *(const float4*)(wrow + e);
        float4 x4 = *(const float4*)(dv + e);
        s += w4.x * x4.x + w4.y * x4.y + w4.z * x4.z + w4.w * x4.w;
    }
    s += __shfl_xor(s, 1, 64);
    if (hf == 0) proj[b * HD + d] = s;
}

// ---------------- mask compaction: per-batch list of UNMASKED tokens ----------
__global__ __launch_bounds__(64) void k_compact(const int* __restrict__ mask,
                                                int* __restrict__ idx,
                                                int* __restrict__ cntblk) {
    const int b = blockIdx.x, ln = threadIdx.x;   // 32 blocks x 64 lanes
    int running = 0;
    for (int s0 = 0; s0 < SS; s0 += 64) {
        int m = mask[b * SS + s0 + ln];
        unsigned long long bal = __ballot(m == 0);
        int pos = __popcll(bal & ((1ull << ln) - 1ull));
        if (m == 0) idx[b * SS + running + pos] = s0 + ln;
        running += __popcll(bal);
    }
    int padded = (running + 63) & ~63;
    for (int i = running + ln; i < padded; i += 64) idx[b * SS + i] = (int)0x80000000;
    if (ln == 0) cntblk[b] = padded >> 6;          // chunk count (<=32)
}

// ---------------- 8-wave 64x1024 scores + exp + partial Z ----------------
// R9: R8 with the load-balance bug fixed. R7/R8 put the XCD swizzle BEFORE
// the chunk->block scan: live chunks (lid < ~530 of 1024) all mapped onto
// XCDs 0-4, XCDs 5-7 got only dead early-exit blocks -> scores 105->201us,
// occupancy 22->10. Fix (R6-proven): lid = blockIdx.x raw. Live lids then
// round-robin across all 8 XCDs. Chunk data is disjoint rows, so XCD L2
// affinity buys nothing anyway; wf (2MB) replicates into every L2.
__global__ __launch_bounds__(512, 2) void k_scores_mfma8b(
        const float* __restrict__ enc,             // [65536][1024] fp32
        const unsigned short* __restrict__ wf,     // fragment-major bf16 W_enc
        const float* __restrict__ V,
        const float* __restrict__ proj,            // [32][1024]
        const int* __restrict__ idx,               // [32][2048] compacted tokens
        const int* __restrict__ cntblk,            // [32] chunk counts
        float* __restrict__ psc,                   // [65536] p = exp(score)
        float* __restrict__ pZ) {                  // [32][32] partial Z
    __shared__ unsigned short SM[8192];            // 16 KB: A dbuf [2][4096]

    const int lid = blockIdx.x;                    // NO swizzle (see header)
    int b = -1, loc = 0;
    {
        int a = 0;
        #pragma unroll
        for (int i = 0; i < 32; i++) {
            int c = cntblk[i];
            if (lid >= a && lid < a + c) { b = i; loc = lid - a; }
            a += c;
        }
    }
    if (b < 0) return;
    const int lt0 = loc << 6;

    const int tid = threadIdx.x;
    const int wv = tid >> 6, ln = tid & 63, l31 = ln & 31, hi = ln >> 5;

    // per-thread A row (K-invariant): gather via compact index
    const int rid = idx[b * SS + lt0 + (tid >> 3)];
    const size_t arow = ((size_t)b * SS + (rid & 0xffff)) * 1024;

    f32x16 acc[2][4];
    #pragma unroll
    for (int m = 0; m < 2; m++)
        #pragma unroll
        for (int n = 0; n < 4; n++)
            #pragma unroll
            for (int r = 0; r < 16; r++) acc[m][n][r] = 0.f;

    float4 areg[2];            // one K-tile of A: 64 rows x 64 k fp32, 8 fp32/thread
    bf16x8 bgE[8], bgF[8];     // B frags: [kk*4+n], E = ks 0,1  F = ks 2,3

    #define LOAD_A(k) do { \
        const float4* g_ = (const float4*)(enc + arow + (k) + (tid & 7) * 8); \
        areg[0] = g_[0]; areg[1] = g_[1]; \
    } while (0)

    #define CVTW_A(buf) do { \
        int row_ = tid >> 3; \
        union { u16x8 s; uint4 u; } pk_; \
        pk_.u.x = pk2(areg[0].x, areg[0].y); \
        pk_.u.y = pk2(areg[0].z, areg[0].w); \
        pk_.u.z = pk2(areg[1].x, areg[1].y); \
        pk_.u.w = pk2(areg[1].z, areg[1].w); \
        *(u16x8*)&SM[(buf) * 4096 + row_ * 64 + (((tid & 7) ^ (row_ & 7)) << 3)] = pk_.s; \
    } while (0)

    // B record: (g = wv*4 + n)*64 + t*4 + ksabs, lane ln
    #define LOADB(bgx, tt, ksb) do { \
        _Pragma("unroll") \
        for (int kk = 0; kk < 2; kk++) \
            _Pragma("unroll") \
            for (int n = 0; n < 4; n++) \
                bgx[kk * 4 + n] = *(const bf16x8*)(wf + ((size_t)((wv * 4 + n) * 64 + (tt) * 4 + (ksb) + kk) * 64 + ln) * 8); \
        } while (0)

    // one half-K-step (2 ks) of the wave-tile: 4 ds_reads + 16 MFMA
    #define HALF(bg, ksb, Ac) do { \
        _Pragma("unroll") \
        for (int kk = 0; kk < 2; kk++) { \
            bf16x8 af0, af1; \
            { int c_ = ((ksb) + kk) * 2 + hi; int row_ = l31; \
              af0 = *(const bf16x8*)&(Ac)[row_ * 64 + ((c_ ^ (row_ & 7)) << 3)]; } \
            { int c_ = ((ksb) + kk) * 2 + hi; int row_ = 32 + l31; \
              af1 = *(const bf16x8*)&(Ac)[row_ * 64 + ((c_ ^ (row_ & 7)) << 3)]; } \
            __builtin_amdgcn_s_setprio(1); \
            _Pragma("unroll") \
            for (int n = 0; n < 4; n++) \
                acc[0][n] = __builtin_amdgcn_mfma_f32_32x32x16_bf16(af0, bg[kk * 4 + n], acc[0][n], 0, 0, 0); \
            _Pragma("unroll") \
            for (int n = 0; n < 4; n++) \
                acc[1][n] = __builtin_amdgcn_mfma_f32_32x32x16_bf16(af1, bg[kk * 4 + n], acc[1][n], 0, 0, 0); \
            __builtin_amdgcn_s_setprio(0); \
        } } while (0)

    // ---- prologue: bg(0) both halves, A(0)->LDS, A(1) in flight ----
    LOADB(bgE, 0, 0); LOADB(bgF, 0, 2);
    LOAD_A(0);
    CVTW_A(0);                 // compiler waits A(0) loads, leaves bg in flight
    LOAD_A(64);                // A(1)
    LGKM0(); BAR();

    for (int t = 0; t < 16; ++t) {
        const int cur = t & 1, nxt = cur ^ 1;
        const unsigned short* Ac = SM + cur * 4096;

        // ks 0,1
        HALF(bgE, 0, Ac);

        // slot: bgE dead -> reload for t+1; convert A(t+1)->LDS nxt; issue A(t+2)
        if (t < 15) {
            LOADB(bgE, t + 1, 0);
            CVTW_A(nxt);                       // counted vmcnt on areg only
            if (t < 14) LOAD_A((t + 2) * 64);
        }

        // ks 2,3
        HALF(bgF, 2, Ac);

        if (t < 15) {
            LOADB(bgF, t + 1, 2);
            LGKM0(); BAR();                    // A dbuf coherence; B stays in flight
        }
    }
    #undef LOAD_A
    #undef CVTW_A
    #undef LOADB
    #undef HALF

    // ---- fused epilogue: sc[m][r] = sum_n V[d]*tanh(acc + proj) ----
    float sc[2][16];
    #pragma unroll
    for (int m = 0; m < 2; m++)
        #pragma unroll
        for (int r = 0; r < 16; r++) sc[m][r] = 0.f;
    #pragma unroll
    for (int n = 0; n < 4; n++) {
        int d = wv * 128 + n * 32 + l31;
        float pd  = proj[b * 1024 + d];
        float vv  = V[d];
        float vv2 = 2.f * vv;
        #pragma unroll
        for (int m = 0; m < 2; m++)
            #pragma unroll
            for (int r = 0; r < 16; r++) {
                float y  = acc[m][n][r] + pd;
                float e2 = __expf(2.f * y);                 // saturates at +/-inf
                float rc = __builtin_amdgcn_rcpf(e2 + 1.f);
                sc[m][r] += vv - vv2 * rc;                  // vv * tanh(y)
            }
    }

    // butterfly sum over the 32-lane column group (halves independent)
    #pragma unroll
    for (int m = 0; m < 2; m++)
        #pragma unroll
        for (int r = 0; r < 16; r++) {
            float v = sc[m][r];
            v += __shfl_xor(v, 1, 64);
            v += __shfl_xor(v, 2, 64);
            v += __shfl_xor(v, 4, 64);
            v += __shfl_xor(v, 8, 64);
            v += __shfl_xor(v, 16, 64);
            sc[m][r] = v;
        }

    __syncthreads();           // all waves done with LDS; safe to alias
    float* redf = (float*)SM;  // [64 tokens][8 waves] f32 = 2KB
    if (l31 == 0) {
        #pragma unroll
        for (int m = 0; m < 2; m++)
            #pragma unroll
            for (int r = 0; r < 16; r++) {
                int tok = m * 32 + (r & 3) + 8 * (r >> 2) + 4 * hi;
                redf[tok * 8 + wv] = sc[m][r];
            }
    }
    __syncthreads();
    if (tid < 64) {
        float s = 0.f;
        #pragma unroll
        for (int w = 0; w < 8; w++) s += redf[tid * 8 + w];
        int sidx = idx[b * SS + lt0 + tid];
        float p = (sidx >= 0) ? __expf(s) : 0.f;   // shift-free softmax: |s|<=51
        if (sidx >= 0) psc[b * SS + sidx] = p;
        float z = p;
        z += __shfl_xor(z, 1, 64);
        z += __shfl_xor(z, 2, 64);
        z += __shfl_xor(z, 4, 64);
        z += __shfl_xor(z, 8, 64);
        z += __shfl_xor(z, 16, 64);
        z += __shfl_xor(z, 32, 64);
        if (tid == 0) pZ[b * 32 + loc] = z;
    }
}

// ---------------- attn normalize: attn = mask ? 0 : p/Z (no trees) ----------
__global__ __launch_bounds__(256) void k_norm(const float* __restrict__ psc,
                                              const int* __restrict__ mask,
                                              const float* __restrict__ pZ,
                                              const int* __restrict__ cntblk,
                                              float* __restrict__ attn) {
    const int b = blockIdx.x, tid = threadIdx.x;
    const int c = cntblk[b];
    float Z = 0.f;
    for (int q = 0; q < c; q++) Z += pZ[b * 32 + q];
    float invZ = 1.f / Z;
    #pragma unroll
    for (int i = 0; i < 8; i++) {
        int s = tid + i * 256;
        int m = mask[b * SS + s];
        float p = m ? 0.f : psc[b * SS + s];
        attn[b * SS + s] = p * invZ;
    }
}

// ---------------- ctx partials: DENSE over compacted rows, high occupancy ----
__global__ __launch_bounds__(256) void k_ctx_dense(const float* __restrict__ enc,
                                                   const float* __restrict__ psc,
                                                   const int* __restrict__ idx,
                                                   const int* __restrict__ cntblk,
                                                   float* __restrict__ pctx) {
    const int b = blockIdx.x, z = blockIdx.y, tid = threadIdx.x;
    if (z >= cntblk[b]) return;
    const int*    ix = idx + b * SS + z * 64;
    const float*  pb = psc + b * SS;
    const float4* e4 = (const float4*)(enc + (size_t)b * SS * 1024);
    float4 acc = {0.f, 0.f, 0.f, 0.f};
    #pragma unroll 4
    for (int s = 0; s < 64; s++) {
        int sidx = ix[s];
        int row  = sidx & 0xffff;                    // sentinel -> row 0
        float p  = (sidx >= 0) ? pb[sidx] : 0.f;     // sentinel -> p = 0
        float4 v = e4[(size_t)row * 256 + tid];
        acc.x = fmaf(p, v.x, acc.x); acc.y = fmaf(p, v.y, acc.y);
        acc.z = fmaf(p, v.z, acc.z); acc.w = fmaf(p, v.w, acc.w);
    }
    *(float4*)(pctx + ((size_t)z * 32 + b) * 1024 + tid * 4) = acc;
}

// ---------------- ctx finalize: ctx = (sum partial N) / Z ----------------
__global__ __launch_bounds__(256) void k_ctx_final(const float* __restrict__ pctx,
                                                   const float* __restrict__ pZ,
                                                   const int* __restrict__ cntblk,
                                                   float* __restrict__ ctx) {
    int i = blockIdx.x * 256 + threadIdx.x;   // 0..32767
    int b = i >> 10, e = i & 1023;
    const int c = cntblk[b];
    float Z = 0.f;
    for (int q = 0; q < c; q++) Z += pZ[b * 32 + q];
    float s = 0.f;
    for (int q = 0; q < c; q++) s += pctx[(size_t)(q * 32 + b) * 1024 + e];
    ctx[i] = s / Z;
}

// ================= fp32 fallback (round-0 proven path) =================
__global__ __launch_bounds__(256) void k_scores_f32(const float* __restrict__ enc,
                                                    const float* __restrict__ W,
                                                    const float* __restrict__ V,
                                                    const float* __restrict__ proj,
                                                    float* __restrict__ scores) {
    __shared__ float As[64][20];
    __shared__ float Bs[64][20];
    __shared__ float red[64][17];
    const int t0 = blockIdx.x * 64;
    const int b  = t0 >> 11;
    const int tid = threadIdx.x;
    const int tx = tid & 15, ty = tid >> 4;
    const int lrow = tid >> 2, lc4 = (tid & 3) * 4;
    float sc[4] = {0.f, 0.f, 0.f, 0.f};
    for (int n0 = 0; n0 < HD; n0 += 64) {
        float C[4][4] = {};
        for (int k0 = 0; k0 < HE; k0 += 16) {
            *(float4*)&As[lrow][lc4] = *(const float4*)(enc + (size_t)(t0 + lrow) * HE + k0 + lc4);
            *(float4*)&Bs[lrow][lc4] = *(const float4*)(W + (size_t)(n0 + lrow) * WROW + k0 + lc4);
            __syncthreads();
            #pragma unroll
            for (int k4 = 0; k4 < 16; k4 += 4) {
                float4 a[4], bb[4];
                #pragma unroll
                for (int i = 0; i < 4; i++) a[i]  = *(float4*)&As[ty * 4 + i][k4];
                #pragma unroll
                for (int j = 0; j < 4; j++) bb[j] = *(float4*)&Bs[tx * 4 + j][k4];
                #pragma unroll
                for (int i = 0; i < 4; i++)
                    #pragma unroll
                    for (int j = 0; j < 4; j++)
                        C[i][j] += a[i].x * bb[j].x + a[i].y * bb[j].y +
                                   a[i].z * bb[j].z + a[i].w * bb[j].w;
            }
            __syncthreads();
        }
        #pragma unroll
        for (int j = 0; j < 4; j++) {
            int d = n0 + tx * 4 + j;
            float pd = proj[b * HD + d];
            float v  = V[d];
            #pragma unroll
            for (int i = 0; i < 4; i++) {
                float y  = C[i][j] + pd;
                float e2 = __expf(2.f * y);
                sc[i] += v * (1.f - 2.f / (e2 + 1.f));
            }
        }
    }
    #pragma unroll
    for (int i = 0; i < 4; i++) red[ty * 4 + i][tx] = sc[i];
    __syncthreads();
    if (tid < 64) {
        float s = 0.f;
        #pragma unroll
        for (int x = 0; x < 16; x++) s += red[tid][x];
        scores[t0 + tid] = s;
    }
}

__global__ __launch_bounds__(256) void k_softmax_f32(float* __restrict__ sc_attn,
                                                     const int* __restrict__ mask) {
    __shared__ float sred[256];
    const int b = blockIdx.x, tid = threadIdx.x;
    float vals[8]; int msk[8];
    float lmax = -1e30f;
    #pragma unroll
    for (int i = 0; i < 8; i++) {
        int s = tid + i * 256;
        vals[i] = sc_attn[b * SS + s];
        msk[i]  = mask[b * SS + s];
        if (!msk[i]) lmax = fmaxf(lmax, vals[i]);
    }
    sred[tid] = lmax; __syncthreads();
    for (int off = 128; off > 0; off >>= 1) {
        if (tid < off) sred[tid] = fmaxf(sred[tid], sred[tid + off]);
        __syncthreads();
    }
    float m = sred[0];
    __syncthreads();
    float ex[8]; float lsum = 0.f;
    #pragma unroll
    for (int i = 0; i < 8; i++) { ex[i] = msk[i] ? 0.f : __expf(vals[i] - m); lsum += ex[i]; }
    sred[tid] = lsum; __syncthreads();
    for (int off = 128; off > 0; off >>= 1) {
        if (tid < off) sred[tid] += sred[tid + off];
        __syncthreads();
    }
    float inv = 1.f / sred[0];
    #pragma unroll
    for (int i = 0; i < 8; i++) sc_attn[b * SS + tid + i * 256] = ex[i] * inv;
}

__global__ __launch_bounds__(256) void k_ctx_atomic(const float* __restrict__ enc,
                                                    const float* __restrict__ attn,
                                                    float* __restrict__ ctx) {
    const int b = blockIdx.x;
    const int e = blockIdx.y * 256 + threadIdx.x;
    const int s0 = blockIdx.z * 256;
    float sum = 0.f;
    for (int s = s0; s < s0 + 256; s++)
        sum += attn[b * SS + s] * enc[((size_t)b * SS + s) * HE + e];
    atomicAdd(&ctx[b * HE + e], sum);
}

extern "C" void kernel_launch(void* const* d_in, const int* in_sizes, int n_in,
                              void* d_out, int out_size, void* d_ws, size_t ws_size,
                              hipStream_t stream) {
    const float* enc  = (const float*)d_in[0];
    const float* dec  = (const float*)d_in[1];
    const int*   mask = (const int*)d_in[2];
    const float* W    = (const float*)d_in[3];
    const float* V    = (const float*)d_in[4];

    float* out  = (float*)d_out;
    float* ctx  = out;               // [32][1024]
    float* attn = out + BB * HE;     // [32][2048]

    // ws layout (bytes): wf 2M | proj 128K | psc 256K | idx 256K | cnt 4K | pZ 4K | pctx 4M
    const size_t WF_OFF = 0, PROJ_OFF = 2097152, PSC_OFF = PROJ_OFF + 131072,
                 IDX_OFF = PSC_OFF + 262144, CNT_OFF = IDX_OFF + 262144,
                 PZ_OFF = CNT_OFF + 4096, PC_OFF = PZ_OFF + 4096,
                 WS_NEED = PC_OFF + 4194304;
    if (ws_size >= WS_NEED) {
        char* w = (char*)d_ws;
        unsigned short* wf = (unsigned short*)(w + WF_OFF);
        float* proj        = (float*)(w + PROJ_OFF);
        float* psc         = (float*)(w + PSC_OFF);
        int*   idx         = (int*)(w + IDX_OFF);
        int*   cntblk      = (int*)(w + CNT_OFF);
        float* pZ          = (float*)(w + PZ_OFF);
        float* pctx        = (float*)(w + PC_OFF);

        k_compact<<<BB, 64, 0, stream>>>(mask, idx, cntblk);
        k_cvt_wfrag<<<512, 256, 0, stream>>>(W, wf);
        k_projdec2<<<256, 256, 0, stream>>>(dec, W, proj);
        k_scores_mfma8b<<<1024, 512, 0, stream>>>(enc, wf, V, proj, idx, cntblk,
                                                  psc, pZ);
        k_norm<<<BB, 256, 0, stream>>>(psc, mask, pZ, cntblk, attn);
        k_ctx_dense<<<dim3(BB, 32), 256, 0, stream>>>(enc, psc, idx, cntblk, pctx);
        k_ctx_final<<<128, 256, 0, stream>>>(pctx, pZ, cntblk, ctx);
    } else {
        float* proj  = ctx;
        float* score = attn;
        k_projdec2<<<256, 256, 0, stream>>>(dec, W, proj);
        k_scores_f32<<<(BB * SS) / 64, 256, 0, stream>>>(enc, W, V, proj, score);
        k_softmax_f32<<<BB, 256, 0, stream>>>(score, mask);
        hipMemsetAsync(ctx, 0, (size_t)BB * HE * sizeof(float), stream);
        k_ctx_atomic<<<dim3(BB, HE / 256, 8), 256, 0, stream>>>(enc, attn, ctx);
    }
}

// Round 10
// 174.096 us; speedup vs baseline: 1.6351x; 1.1098x over previous
//
#include <hip/hip_runtime.h>
#include <hip/hip_bf16.h>
#include <math.h>

#define BB 32
#define SS 2048
#define HE 1024
#define HD 1024
#define WROW (HE + HD)   // 2048

typedef __attribute__((ext_vector_type(8))) short bf16x8;
typedef __attribute__((ext_vector_type(4))) float f32x4;
typedef __attribute__((ext_vector_type(16))) float f32x16;
typedef __attribute__((ext_vector_type(8))) unsigned short u16x8;

__device__ __forceinline__ unsigned short f2bf(float f) {
    union { float f; unsigned u; } v; v.f = f;
    unsigned r = v.u + 0x7fffu + ((v.u >> 16) & 1u);   // RNE
    return (unsigned short)(r >> 16);
}

__device__ __forceinline__ unsigned int pk2(float x, float y) {
    union { __hip_bfloat162 h; unsigned int u; } c;
    c.h = __float22bfloat162_rn(float2{x, y});          // v_cvt_pk_bf16_f32
    return c.u;
}

#define LGKM0()  asm volatile("s_waitcnt lgkmcnt(0)" ::: "memory")
#define BAR()    asm volatile("s_barrier" ::: "memory")

// ---------------- k_prep: compact | cvt_wfrag | proj_dec fused ----------------
// R10: the three prep kernels were ~20us of serialized small dispatches; the
// compact section is latency-bound (32 waves total, serial ballot scan) and
// previously ran with the GPU otherwise idle. Fused as grid sections, compact
// (bx<32, launched first) overlaps cvt (32..543) and proj (544..799).
// Section bodies are bit-identical to the R6-R9-proven standalone kernels.
__global__ __launch_bounds__(256) void k_prep(const float* __restrict__ W,
                                              const float* __restrict__ dec,
                                              const int* __restrict__ mask,
                                              unsigned short* __restrict__ wf,
                                              float* __restrict__ proj,
                                              int* __restrict__ idx,
                                              int* __restrict__ cntblk) {
    const int bx = blockIdx.x, tid = threadIdx.x;
    if (bx < 32) {
        // ---- compact: per-batch list of UNMASKED tokens (wave 0 only) ----
        if (tid >= 64) return;
        const int b = bx, ln = tid;
        int running = 0;
        for (int s0 = 0; s0 < SS; s0 += 64) {
            int m = mask[b * SS + s0 + ln];
            unsigned long long bal = __ballot(m == 0);
            int pos = __popcll(bal & ((1ull << ln) - 1ull));
            if (m == 0) idx[b * SS + running + pos] = s0 + ln;
            running += __popcll(bal);
        }
        int padded = (running + 63) & ~63;
        for (int i = running + ln; i < padded; i += 64) idx[b * SS + i] = (int)0x80000000;
        if (ln == 0) cntblk[b] = padded >> 6;          // chunk count (<=32)
    } else if (bx < 544) {
        // ---- cvt: W_enc fp32 -> bf16 fragment-major (32x32x16 records) ----
        // lane l of record (g,ks) = W[d=g*32+(l&31)][k=ks*16+(l>>5)*8 ..+8]
        int i = (bx - 32) * 256 + tid;             // 0..131071 (8-elem chunks)
        int d = i >> 7;                            // 0..1023
        int c = i & 127;                           // k-chunk: k = c*8
        const float4* src = (const float4*)(W + (size_t)d * WROW + c * 8);
        float4 a = src[0], b2 = src[1];
        u16x8 o;
        o[0] = f2bf(a.x);  o[1] = f2bf(a.y);  o[2] = f2bf(a.z);  o[3] = f2bf(a.w);
        o[4] = f2bf(b2.x); o[5] = f2bf(b2.y); o[6] = f2bf(b2.z); o[7] = f2bf(b2.w);
        int ks = c >> 1;                           // k>>4
        int l  = (d & 31) + 32 * (c & 1);          // (l>>5) = k-half
        int g  = d >> 5;
        *(u16x8*)(wf + ((size_t)(g * 64 + ks) * 64 + l) * 8) = o;
    } else {
        // ---- proj_dec: W_dec read ONCE total ----
        const int dl = tid >> 6;
        const int b  = (tid >> 1) & 31;
        const int hf = tid & 1;
        const int d  = (bx - 544) * 4 + dl;
        const float* wrow = W + (size_t)d * WROW + HE + hf * 512;
        const float* dv   = dec + b * HD + hf * 512;
        float s = 0.f;
        #pragma unroll 4
        for (int e = 0; e < 512; e += 4) {
            float4 w4 = *(const float4*)(wrow + e);
            float4 x4 = *(const float4*)(dv + e);
            s += w4.x * x4.x + w4.y * x4.y + w4.z * x4.z + w4.w * x4.w;
        }
        s += __shfl_xor(s, 1, 64);
        if (hf == 0) proj[b * HD + d] = s;
    }
}

// ---------------- 8-wave 64x1024 scores + exp + partial Z (R9-proven) --------
__global__ __launch_bounds__(512, 2) void k_scores_mfma8b(
        const float* __restrict__ enc,             // [65536][1024] fp32
        const unsigned short* __restrict__ wf,     // fragment-major bf16 W_enc
        const float* __restrict__ V,
        const float* __restrict__ proj,            // [32][1024]
        const int* __restrict__ idx,               // [32][2048] compacted tokens
        const int* __restrict__ cntblk,            // [32] chunk counts
        float* __restrict__ psc,                   // [65536] p = exp(score)
        float* __restrict__ pZ) {                  // [32][32] partial Z
    __shared__ unsigned short SM[8192];            // 16 KB: A dbuf [2][4096]

    const int lid = blockIdx.x;                    // no swizzle (R9: balance fix)
    int b = -1, loc = 0;
    {
        int a = 0;
        #pragma unroll
        for (int i = 0; i < 32; i++) {
            int c = cntblk[i];
            if (lid >= a && lid < a + c) { b = i; loc = lid - a; }
            a += c;
        }
    }
    if (b < 0) return;
    const int lt0 = loc << 6;

    const int tid = threadIdx.x;
    const int wv = tid >> 6, ln = tid & 63, l31 = ln & 31, hi = ln >> 5;

    // per-thread A row (K-invariant): gather via compact index
    const int rid = idx[b * SS + lt0 + (tid >> 3)];
    const size_t arow = ((size_t)b * SS + (rid & 0xffff)) * 1024;

    f32x16 acc[2][4];
    #pragma unroll
    for (int m = 0; m < 2; m++)
        #pragma unroll
        for (int n = 0; n < 4; n++)
            #pragma unroll
            for (int r = 0; r < 16; r++) acc[m][n][r] = 0.f;

    float4 areg[2];            // one K-tile of A: 64 rows x 64 k fp32, 8 fp32/thread
    bf16x8 bgE[8], bgF[8];     // B frags: [kk*4+n], E = ks 0,1  F = ks 2,3

    #define LOAD_A(k) do { \
        const float4* g_ = (const float4*)(enc + arow + (k) + (tid & 7) * 8); \
        areg[0] = g_[0]; areg[1] = g_[1]; \
    } while (0)

    #define CVTW_A(buf) do { \
        int row_ = tid >> 3; \
        union { u16x8 s; uint4 u; } pk_; \
        pk_.u.x = pk2(areg[0].x, areg[0].y); \
        pk_.u.y = pk2(areg[0].z, areg[0].w); \
        pk_.u.z = pk2(areg[1].x, areg[1].y); \
        pk_.u.w = pk2(areg[1].z, areg[1].w); \
        *(u16x8*)&SM[(buf) * 4096 + row_ * 64 + (((tid & 7) ^ (row_ & 7)) << 3)] = pk_.s; \
    } while (0)

    // B record: (g = wv*4 + n)*64 + t*4 + ksabs, lane ln
    #define LOADB(bgx, tt, ksb) do { \
        _Pragma("unroll") \
        for (int kk = 0; kk < 2; kk++) \
            _Pragma("unroll") \
            for (int n = 0; n < 4; n++) \
                bgx[kk * 4 + n] = *(const bf16x8*)(wf + ((size_t)((wv * 4 + n) * 64 + (tt) * 4 + (ksb) + kk) * 64 + ln) * 8); \
        } while (0)

    // one half-K-step (2 ks) of the wave-tile: 4 ds_reads + 16 MFMA
    #define HALF(bg, ksb, Ac) do { \
        _Pragma("unroll") \
        for (int kk = 0; kk < 2; kk++) { \
            bf16x8 af0, af1; \
            { int c_ = ((ksb) + kk) * 2 + hi; int row_ = l31; \
              af0 = *(const bf16x8*)&(Ac)[row_ * 64 + ((c_ ^ (row_ & 7)) << 3)]; } \
            { int c_ = ((ksb) + kk) * 2 + hi; int row_ = 32 + l31; \
              af1 = *(const bf16x8*)&(Ac)[row_ * 64 + ((c_ ^ (row_ & 7)) << 3)]; } \
            __builtin_amdgcn_s_setprio(1); \
            _Pragma("unroll") \
            for (int n = 0; n < 4; n++) \
                acc[0][n] = __builtin_amdgcn_mfma_f32_32x32x16_bf16(af0, bg[kk * 4 + n], acc[0][n], 0, 0, 0); \
            _Pragma("unroll") \
            for (int n = 0; n < 4; n++) \
                acc[1][n] = __builtin_amdgcn_mfma_f32_32x32x16_bf16(af1, bg[kk * 4 + n], acc[1][n], 0, 0, 0); \
            __builtin_amdgcn_s_setprio(0); \
        } } while (0)

    // ---- prologue: bg(0) both halves, A(0)->LDS, A(1) in flight ----
    LOADB(bgE, 0, 0); LOADB(bgF, 0, 2);
    LOAD_A(0);
    CVTW_A(0);                 // compiler waits A(0) loads, leaves bg in flight
    LOAD_A(64);                // A(1)
    LGKM0(); BAR();

    for (int t = 0; t < 16; ++t) {
        const int cur = t & 1, nxt = cur ^ 1;
        const unsigned short* Ac = SM + cur * 4096;

        // ks 0,1
        HALF(bgE, 0, Ac);

        // slot: bgE dead -> reload for t+1; convert A(t+1)->LDS nxt; issue A(t+2)
        if (t < 15) {
            LOADB(bgE, t + 1, 0);
            CVTW_A(nxt);                       // counted vmcnt on areg only
            if (t < 14) LOAD_A((t + 2) * 64);
        }

        // ks 2,3
        HALF(bgF, 2, Ac);

        if (t < 15) {
            LOADB(bgF, t + 1, 2);
            LGKM0(); BAR();                    // A dbuf coherence; B stays in flight
        }
    }
    #undef LOAD_A
    #undef CVTW_A
    #undef LOADB
    #undef HALF

    // ---- fused epilogue: sc[m][r] = sum_n V[d]*tanh(acc + proj) ----
    float sc[2][16];
    #pragma unroll
    for (int m = 0; m < 2; m++)
        #pragma unroll
        for (int r = 0; r < 16; r++) sc[m][r] = 0.f;
    #pragma unroll
    for (int n = 0; n < 4; n++) {
        int d = wv * 128 + n * 32 + l31;
        float pd  = proj[b * 1024 + d];
        float vv  = V[d];
        float vv2 = 2.f * vv;
        #pragma unroll
        for (int m = 0; m < 2; m++)
            #pragma unroll
            for (int r = 0; r < 16; r++) {
                float y  = acc[m][n][r] + pd;
                float e2 = __expf(2.f * y);                 // saturates at +/-inf
                float rc = __builtin_amdgcn_rcpf(e2 + 1.f);
                sc[m][r] += vv - vv2 * rc;                  // vv * tanh(y)
            }
    }

    // butterfly sum over the 32-lane column group (halves independent)
    #pragma unroll
    for (int m = 0; m < 2; m++)
        #pragma unroll
        for (int r = 0; r < 16; r++) {
            float v = sc[m][r];
            v += __shfl_xor(v, 1, 64);
            v += __shfl_xor(v, 2, 64);
            v += __shfl_xor(v, 4, 64);
            v += __shfl_xor(v, 8, 64);
            v += __shfl_xor(v, 16, 64);
            sc[m][r] = v;
        }

    __syncthreads();           // all waves done with LDS; safe to alias
    float* redf = (float*)SM;  // [64 tokens][8 waves] f32 = 2KB
    if (l31 == 0) {
        #pragma unroll
        for (int m = 0; m < 2; m++)
            #pragma unroll
            for (int r = 0; r < 16; r++) {
                int tok = m * 32 + (r & 3) + 8 * (r >> 2) + 4 * hi;
                redf[tok * 8 + wv] = sc[m][r];
            }
    }
    __syncthreads();
    if (tid < 64) {
        float s = 0.f;
        #pragma unroll
        for (int w = 0; w < 8; w++) s += redf[tid * 8 + w];
        int sidx = idx[b * SS + lt0 + tid];
        float p = (sidx >= 0) ? __expf(s) : 0.f;   // shift-free softmax: |s|<=51
        if (sidx >= 0) psc[b * SS + sidx] = p;
        float z = p;
        z += __shfl_xor(z, 1, 64);
        z += __shfl_xor(z, 2, 64);
        z += __shfl_xor(z, 4, 64);
        z += __shfl_xor(z, 8, 64);
        z += __shfl_xor(z, 16, 64);
        z += __shfl_xor(z, 32, 64);
        if (tid == 0) pZ[b * 32 + loc] = z;
    }
}

// ---------------- ctx partials (z<32) | attn normalize (z==32) fused ---------
__global__ __launch_bounds__(256) void k_ctx_norm(const float* __restrict__ enc,
                                                  const float* __restrict__ psc,
                                                  const int* __restrict__ idx,
                                                  const int* __restrict__ cntblk,
                                                  const int* __restrict__ mask,
                                                  const float* __restrict__ pZ,
                                                  float* __restrict__ pctx,
                                                  float* __restrict__ attn) {
    const int b = blockIdx.x, z = blockIdx.y, tid = threadIdx.x;
    if (z == 32) {
        // ---- norm: attn = mask ? 0 : p/Z ----
        const int c = cntblk[b];
        float Z = 0.f;
        for (int q = 0; q < c; q++) Z += pZ[b * 32 + q];
        float invZ = 1.f / Z;
        #pragma unroll
        for (int i = 0; i < 8; i++) {
            int s = tid + i * 256;
            int m = mask[b * SS + s];
            float p = m ? 0.f : psc[b * SS + s];
            attn[b * SS + s] = p * invZ;
        }
        return;
    }
    // ---- ctx partial: dense over compacted rows, high occupancy ----
    if (z >= cntblk[b]) return;
    const int*    ix = idx + b * SS + z * 64;
    const float*  pb = psc + b * SS;
    const float4* e4 = (const float4*)(enc + (size_t)b * SS * 1024);
    float4 acc = {0.f, 0.f, 0.f, 0.f};
    #pragma unroll 4
    for (int s = 0; s < 64; s++) {
        int sidx = ix[s];
        int row  = sidx & 0xffff;                    // sentinel -> row 0
        float p  = (sidx >= 0) ? pb[sidx] : 0.f;     // sentinel -> p = 0
        float4 v = e4[(size_t)row * 256 + tid];
        acc.x = fmaf(p, v.x, acc.x); acc.y = fmaf(p, v.y, acc.y);
        acc.z = fmaf(p, v.z, acc.z); acc.w = fmaf(p, v.w, acc.w);
    }
    *(float4*)(pctx + ((size_t)z * 32 + b) * 1024 + tid * 4) = acc;
}

// ---------------- ctx finalize: ctx = (sum partial N) / Z ----------------
__global__ __launch_bounds__(256) void k_ctx_final(const float* __restrict__ pctx,
                                                   const float* __restrict__ pZ,
                                                   const int* __restrict__ cntblk,
                                                   float* __restrict__ ctx) {
    int i = blockIdx.x * 256 + threadIdx.x;   // 0..32767
    int b = i >> 10, e = i & 1023;
    const int c = cntblk[b];
    float Z = 0.f;
    for (int q = 0; q < c; q++) Z += pZ[b * 32 + q];
    float s = 0.f;
    for (int q = 0; q < c; q++) s += pctx[(size_t)(q * 32 + b) * 1024 + e];
    ctx[i] = s / Z;
}

// ================= fp32 fallback (round-0 proven path) =================
__global__ __launch_bounds__(256) void k_projdec2(const float* __restrict__ dec,
                                                  const float* __restrict__ W,
                                                  float* __restrict__ proj) {
    const int tid = threadIdx.x;
    const int dl = tid >> 6;
    const int b  = (tid >> 1) & 31;
    const int hf = tid & 1;
    const int d  = blockIdx.x * 4 + dl;
    const float* wrow = W + (size_t)d * WROW + HE + hf * 512;
    const float* dv   = dec + b * HD + hf * 512;
    float s = 0.f;
    #pragma unroll 4
    for (int e = 0; e < 512; e += 4) {
        float4 w4 = *(const float4*)(wrow + e);
        float4 x4 = *(const float4*)(dv + e);
        s += w4.x * x4.x + w4.y * x4.y + w4.z * x4.z + w4.w * x4.w;
    }
    s += __shfl_xor(s, 1, 64);
    if (hf == 0) proj[b * HD + d] = s;
}

__global__ __launch_bounds__(256) void k_scores_f32(const float* __restrict__ enc,
                                                    const float* __restrict__ W,
                                                    const float* __restrict__ V,
                                                    const float* __restrict__ proj,
                                                    float* __restrict__ scores) {
    __shared__ float As[64][20];
    __shared__ float Bs[64][20];
    __shared__ float red[64][17];
    const int t0 = blockIdx.x * 64;
    const int b  = t0 >> 11;
    const int tid = threadIdx.x;
    const int tx = tid & 15, ty = tid >> 4;
    const int lrow = tid >> 2, lc4 = (tid & 3) * 4;
    float sc[4] = {0.f, 0.f, 0.f, 0.f};
    for (int n0 = 0; n0 < HD; n0 += 64) {
        float C[4][4] = {};
        for (int k0 = 0; k0 < HE; k0 += 16) {
            *(float4*)&As[lrow][lc4] = *(const float4*)(enc + (size_t)(t0 + lrow) * HE + k0 + lc4);
            *(float4*)&Bs[lrow][lc4] = *(const float4*)(W + (size_t)(n0 + lrow) * WROW + k0 + lc4);
            __syncthreads();
            #pragma unroll
            for (int k4 = 0; k4 < 16; k4 += 4) {
                float4 a[4], bb[4];
                #pragma unroll
                for (int i = 0; i < 4; i++) a[i]  = *(float4*)&As[ty * 4 + i][k4];
                #pragma unroll
                for (int j = 0; j < 4; j++) bb[j] = *(float4*)&Bs[tx * 4 + j][k4];
                #pragma unroll
                for (int i = 0; i < 4; i++)
                    #pragma unroll
                    for (int j = 0; j < 4; j++)
                        C[i][j] += a[i].x * bb[j].x + a[i].y * bb[j].y +
                                   a[i].z * bb[j].z + a[i].w * bb[j].w;
            }
            __syncthreads();
        }
        #pragma unroll
        for (int j = 0; j < 4; j++) {
            int d = n0 + tx * 4 + j;
            float pd = proj[b * HD + d];
            float v  = V[d];
            #pragma unroll
            for (int i = 0; i < 4; i++) {
                float y  = C[i][j] + pd;
                float e2 = __expf(2.f * y);
                sc[i] += v * (1.f - 2.f / (e2 + 1.f));
            }
        }
    }
    #pragma unroll
    for (int i = 0; i < 4; i++) red[ty * 4 + i][tx] = sc[i];
    __syncthreads();
    if (tid < 64) {
        float s = 0.f;
        #pragma unroll
        for (int x = 0; x < 16; x++) s += red[tid][x];
        scores[t0 + tid] = s;
    }
}

__global__ __launch_bounds__(256) void k_softmax_f32(float* __restrict__ sc_attn,
                                                     const int* __restrict__ mask) {
    __shared__ float sred[256];
    const int b = blockIdx.x, tid = threadIdx.x;
    float vals[8]; int msk[8];
    float lmax = -1e30f;
    #pragma unroll
    for (int i = 0; i < 8; i++) {
        int s = tid + i * 256;
        vals[i] = sc_attn[b * SS + s];
        msk[i]  = mask[b * SS + s];
        if (!msk[i]) lmax = fmaxf(lmax, vals[i]);
    }
    sred[tid] = lmax; __syncthreads();
    for (int off = 128; off > 0; off >>= 1) {
        if (tid < off) sred[tid] = fmaxf(sred[tid], sred[tid + off]);
        __syncthreads();
    }
    float m = sred[0];
    __syncthreads();
    float ex[8]; float lsum = 0.f;
    #pragma unroll
    for (int i = 0; i < 8; i++) { ex[i] = msk[i] ? 0.f : __expf(vals[i] - m); lsum += ex[i]; }
    sred[tid] = lsum; __syncthreads();
    for (int off = 128; off > 0; off >>= 1) {
        if (tid < off) sred[tid] += sred[tid + off];
        __syncthreads();
    }
    float inv = 1.f / sred[0];
    #pragma unroll
    for (int i = 0; i < 8; i++) sc_attn[b * SS + tid + i * 256] = ex[i] * inv;
}

__global__ __launch_bounds__(256) void k_ctx_atomic(const float* __restrict__ enc,
                                                    const float* __restrict__ attn,
                                                    float* __restrict__ ctx) {
    const int b = blockIdx.x;
    const int e = blockIdx.y * 256 + threadIdx.x;
    const int s0 = blockIdx.z * 256;
    float sum = 0.f;
    for (int s = s0; s < s0 + 256; s++)
        sum += attn[b * SS + s] * enc[((size_t)b * SS + s) * HE + e];
    atomicAdd(&ctx[b * HE + e], sum);
}

extern "C" void kernel_launch(void* const* d_in, const int* in_sizes, int n_in,
                              void* d_out, int out_size, void* d_ws, size_t ws_size,
                              hipStream_t stream) {
    const float* enc  = (const float*)d_in[0];
    const float* dec  = (const float*)d_in[1];
    const int*   mask = (const int*)d_in[2];
    const float* W    = (const float*)d_in[3];
    const float* V    = (const float*)d_in[4];

    float* out  = (float*)d_out;
    float* ctx  = out;               // [32][1024]
    float* attn = out + BB * HE;     // [32][2048]

    // ws layout (bytes): wf 2M | proj 128K | psc 256K | idx 256K | cnt 4K | pZ 4K | pctx 4M
    const size_t WF_OFF = 0, PROJ_OFF = 2097152, PSC_OFF = PROJ_OFF + 131072,
                 IDX_OFF = PSC_OFF + 262144, CNT_OFF = IDX_OFF + 262144,
                 PZ_OFF = CNT_OFF + 4096, PC_OFF = PZ_OFF + 4096,
                 WS_NEED = PC_OFF + 4194304;
    if (ws_size >= WS_NEED) {
        char* w = (char*)d_ws;
        unsigned short* wf = (unsigned short*)(w + WF_OFF);
        float* proj        = (float*)(w + PROJ_OFF);
        float* psc         = (float*)(w + PSC_OFF);
        int*   idx         = (int*)(w + IDX_OFF);
        int*   cntblk      = (int*)(w + CNT_OFF);
        float* pZ          = (float*)(w + PZ_OFF);
        float* pctx        = (float*)(w + PC_OFF);

        k_prep<<<800, 256, 0, stream>>>(W, dec, mask, wf, proj, idx, cntblk);
        k_scores_mfma8b<<<1024, 512, 0, stream>>>(enc, wf, V, proj, idx, cntblk,
                                                  psc, pZ);
        k_ctx_norm<<<dim3(BB, 33), 256, 0, stream>>>(enc, psc, idx, cntblk, mask,
                                                     pZ, pctx, attn);
        k_ctx_final<<<128, 256, 0, stream>>>(pctx, pZ, cntblk, ctx);
    } else {
        float* proj  = ctx;
        float* score = attn;
        k_projdec2<<<256, 256, 0, stream>>>(dec, W, proj);
        k_scores_f32<<<(BB * SS) / 64, 256, 0, stream>>>(enc, W, V, proj, score);
        k_softmax_f32<<<BB, 256, 0, stream>>>(score, mask);
        hipMemsetAsync(ctx, 0, (size_t)BB * HE * sizeof(float), stream);
        k_ctx_atomic<<<dim3(BB, HE / 256, 8), 256, 0, stream>>>(enc, attn, ctx);
    }
}

// Round 11
// 171.932 us; speedup vs baseline: 1.6557x; 1.0126x over previous
//
#include <hip/hip_runtime.h>
#include <hip/hip_bf16.h>
#include <math.h>

#define BB 32
#define SS 2048
#define HE 1024
#define HD 1024
#define WROW (HE + HD)   // 2048

typedef __attribute__((ext_vector_type(8))) short bf16x8;
typedef __attribute__((ext_vector_type(4))) float f32x4;
typedef __attribute__((ext_vector_type(16))) float f32x16;
typedef __attribute__((ext_vector_type(8))) unsigned short u16x8;

__device__ __forceinline__ unsigned short f2bf(float f) {
    union { float f; unsigned u; } v; v.f = f;
    unsigned r = v.u + 0x7fffu + ((v.u >> 16) & 1u);   // RNE
    return (unsigned short)(r >> 16);
}

__device__ __forceinline__ unsigned int pk2(float x, float y) {
    union { __hip_bfloat162 h; unsigned int u; } c;
    c.h = __float22bfloat162_rn(float2{x, y});          // v_cvt_pk_bf16_f32
    return c.u;
}

#define LGKM0()  asm volatile("s_waitcnt lgkmcnt(0)" ::: "memory")
#define BAR()    asm volatile("s_barrier" ::: "memory")

// ---------------- k_prep: compact | cvt_wfrag | proj_dec fused ----------------
// R11: compact section parallelized 1 wave -> 4 waves per batch (was a serial
// 32-iteration ballot scan ~8us on the critical path; now 8 iters/wave + LDS
// slab merge). cvt/proj sections unchanged (R10-proven).
__global__ __launch_bounds__(256) void k_prep(const float* __restrict__ W,
                                              const float* __restrict__ dec,
                                              const int* __restrict__ mask,
                                              unsigned short* __restrict__ wf,
                                              float* __restrict__ proj,
                                              int* __restrict__ idx,
                                              int* __restrict__ cntblk) {
    __shared__ int cb[2048];
    __shared__ int cw[4], coff[5];
    const int bx = blockIdx.x, tid = threadIdx.x;
    if (bx < 32) {
        // ---- compact: 4 waves, each scans a 512-token quarter into its slab ----
        const int b = bx, w = tid >> 6, ln = tid & 63;
        const int base = w * 512;
        int cnt = 0;
        for (int r = 0; r < 8; r++) {
            int s = base + r * 64 + ln;
            int m = mask[b * SS + s];
            unsigned long long bal = __ballot(m == 0);
            int pos = __popcll(bal & ((1ull << ln) - 1ull));
            if (m == 0) cb[base + cnt + pos] = s;
            cnt += __popcll(bal);
        }
        if (ln == 0) cw[w] = cnt;
        __syncthreads();
        if (tid == 0) {
            coff[0] = 0;
            for (int q = 0; q < 4; q++) coff[q + 1] = coff[q] + cw[q];
        }
        __syncthreads();
        const int total = coff[4];
        for (int i = tid; i < total; i += 256) {
            int q = (i >= coff[1]) + (i >= coff[2]) + (i >= coff[3]);
            idx[b * SS + i] = cb[q * 512 + (i - coff[q])];
        }
        const int padded = (total + 63) & ~63;
        for (int i = total + tid; i < padded; i += 256) idx[b * SS + i] = (int)0x80000000;
        if (tid == 0) cntblk[b] = padded >> 6;         // chunk count (<=32)
    } else if (bx < 544) {
        // ---- cvt: W_enc fp32 -> bf16 fragment-major (32x32x16 records) ----
        int i = (bx - 32) * 256 + tid;             // 0..131071 (8-elem chunks)
        int d = i >> 7;                            // 0..1023
        int c = i & 127;                           // k-chunk: k = c*8
        const float4* src = (const float4*)(W + (size_t)d * WROW + c * 8);
        float4 a = src[0], b2 = src[1];
        u16x8 o;
        o[0] = f2bf(a.x);  o[1] = f2bf(a.y);  o[2] = f2bf(a.z);  o[3] = f2bf(a.w);
        o[4] = f2bf(b2.x); o[5] = f2bf(b2.y); o[6] = f2bf(b2.z); o[7] = f2bf(b2.w);
        int ks = c >> 1;                           // k>>4
        int l  = (d & 31) + 32 * (c & 1);          // (l>>5) = k-half
        int g  = d >> 5;
        *(u16x8*)(wf + ((size_t)(g * 64 + ks) * 64 + l) * 8) = o;
    } else {
        // ---- proj_dec: W_dec read ONCE total ----
        const int dl = tid >> 6;
        const int b  = (tid >> 1) & 31;
        const int hf = tid & 1;
        const int d  = (bx - 544) * 4 + dl;
        const float* wrow = W + (size_t)d * WROW + HE + hf * 512;
        const float* dv   = dec + b * HD + hf * 512;
        float s = 0.f;
        #pragma unroll 4
        for (int e = 0; e < 512; e += 4) {
            float4 w4 = *(const float4*)(wrow + e);
            float4 x4 = *(const float4*)(dv + e);
            s += w4.x * x4.x + w4.y * x4.y + w4.z * x4.z + w4.w * x4.w;
        }
        s += __shfl_xor(s, 1, 64);
        if (hf == 0) proj[b * HD + d] = s;
    }
}

// ---------------- 8-wave 64x1024 scores + exp + partial Z + fused PV ---------
// R11: R9/R10 core + the R7 PV concept with the implementation fixed. R7's PV
// regression is de-confounded: the XCD-swizzle imbalance cost ~50us (R8), and
// the PV loop itself was rolled+divergent (if(p!=0), dependent loads, MLP~1).
// Here: branch-free (sentinel -> row0 x p=0), #pragma unroll 8 (16 loads in
// flight/wave), p from LDS, coalesced L2-warm row reads the block itself just
// staged. Eliminates the separate 134MB enc re-read pass (~20us).
__global__ __launch_bounds__(512, 2) void k_scores_mfma8b(
        const float* __restrict__ enc,             // [65536][1024] fp32
        const unsigned short* __restrict__ wf,     // fragment-major bf16 W_enc
        const float* __restrict__ V,
        const float* __restrict__ proj,            // [32][1024]
        const int* __restrict__ idx,               // [32][2048] compacted tokens
        const int* __restrict__ cntblk,            // [32] chunk counts
        float* __restrict__ psc,                   // [65536] p = exp(score)
        float* __restrict__ pZ,                    // [32][32] partial Z
        float* __restrict__ pnum) {                // [32][32][1024] partial ctx num
    __shared__ unsigned short SM[8192];            // 16 KB: A dbuf [2][4096]

    const int lid = blockIdx.x;                    // no swizzle (R9: balance fix)
    int b = -1, loc = 0;
    {
        int a = 0;
        #pragma unroll
        for (int i = 0; i < 32; i++) {
            int c = cntblk[i];
            if (lid >= a && lid < a + c) { b = i; loc = lid - a; }
            a += c;
        }
    }
    if (b < 0) return;
    const int lt0 = loc << 6;

    const int tid = threadIdx.x;
    const int wv = tid >> 6, ln = tid & 63, l31 = ln & 31, hi = ln >> 5;

    // per-thread A row (K-invariant): gather via compact index
    const int rid = idx[b * SS + lt0 + (tid >> 3)];
    const size_t arow = ((size_t)b * SS + (rid & 0xffff)) * 1024;

    f32x16 acc[2][4];
    #pragma unroll
    for (int m = 0; m < 2; m++)
        #pragma unroll
        for (int n = 0; n < 4; n++)
            #pragma unroll
            for (int r = 0; r < 16; r++) acc[m][n][r] = 0.f;

    float4 areg[2];            // one K-tile of A: 64 rows x 64 k fp32, 8 fp32/thread
    bf16x8 bgE[8], bgF[8];     // B frags: [kk*4+n], E = ks 0,1  F = ks 2,3

    #define LOAD_A(k) do { \
        const float4* g_ = (const float4*)(enc + arow + (k) + (tid & 7) * 8); \
        areg[0] = g_[0]; areg[1] = g_[1]; \
    } while (0)

    #define CVTW_A(buf) do { \
        int row_ = tid >> 3; \
        union { u16x8 s; uint4 u; } pk_; \
        pk_.u.x = pk2(areg[0].x, areg[0].y); \
        pk_.u.y = pk2(areg[0].z, areg[0].w); \
        pk_.u.z = pk2(areg[1].x, areg[1].y); \
        pk_.u.w = pk2(areg[1].z, areg[1].w); \
        *(u16x8*)&SM[(buf) * 4096 + row_ * 64 + (((tid & 7) ^ (row_ & 7)) << 3)] = pk_.s; \
    } while (0)

    // B record: (g = wv*4 + n)*64 + t*4 + ksabs, lane ln
    #define LOADB(bgx, tt, ksb) do { \
        _Pragma("unroll") \
        for (int kk = 0; kk < 2; kk++) \
            _Pragma("unroll") \
            for (int n = 0; n < 4; n++) \
                bgx[kk * 4 + n] = *(const bf16x8*)(wf + ((size_t)((wv * 4 + n) * 64 + (tt) * 4 + (ksb) + kk) * 64 + ln) * 8); \
        } while (0)

    // one half-K-step (2 ks) of the wave-tile: 4 ds_reads + 16 MFMA
    #define HALF(bg, ksb, Ac) do { \
        _Pragma("unroll") \
        for (int kk = 0; kk < 2; kk++) { \
            bf16x8 af0, af1; \
            { int c_ = ((ksb) + kk) * 2 + hi; int row_ = l31; \
              af0 = *(const bf16x8*)&(Ac)[row_ * 64 + ((c_ ^ (row_ & 7)) << 3)]; } \
            { int c_ = ((ksb) + kk) * 2 + hi; int row_ = 32 + l31; \
              af1 = *(const bf16x8*)&(Ac)[row_ * 64 + ((c_ ^ (row_ & 7)) << 3)]; } \
            __builtin_amdgcn_s_setprio(1); \
            _Pragma("unroll") \
            for (int n = 0; n < 4; n++) \
                acc[0][n] = __builtin_amdgcn_mfma_f32_32x32x16_bf16(af0, bg[kk * 4 + n], acc[0][n], 0, 0, 0); \
            _Pragma("unroll") \
            for (int n = 0; n < 4; n++) \
                acc[1][n] = __builtin_amdgcn_mfma_f32_32x32x16_bf16(af1, bg[kk * 4 + n], acc[1][n], 0, 0, 0); \
            __builtin_amdgcn_s_setprio(0); \
        } } while (0)

    // ---- prologue: bg(0) both halves, A(0)->LDS, A(1) in flight ----
    LOADB(bgE, 0, 0); LOADB(bgF, 0, 2);
    LOAD_A(0);
    CVTW_A(0);                 // compiler waits A(0) loads, leaves bg in flight
    LOAD_A(64);                // A(1)
    LGKM0(); BAR();

    for (int t = 0; t < 16; ++t) {
        const int cur = t & 1, nxt = cur ^ 1;
        const unsigned short* Ac = SM + cur * 4096;

        // ks 0,1
        HALF(bgE, 0, Ac);

        // slot: bgE dead -> reload for t+1; convert A(t+1)->LDS nxt; issue A(t+2)
        if (t < 15) {
            LOADB(bgE, t + 1, 0);
            CVTW_A(nxt);                       // counted vmcnt on areg only
            if (t < 14) LOAD_A((t + 2) * 64);
        }

        // ks 2,3
        HALF(bgF, 2, Ac);

        if (t < 15) {
            LOADB(bgF, t + 1, 2);
            LGKM0(); BAR();                    // A dbuf coherence; B stays in flight
        }
    }
    #undef LOAD_A
    #undef CVTW_A
    #undef LOADB
    #undef HALF

    // ---- fused epilogue: sc[m][r] = sum_n V[d]*tanh(acc + proj) ----
    float sc[2][16];
    #pragma unroll
    for (int m = 0; m < 2; m++)
        #pragma unroll
        for (int r = 0; r < 16; r++) sc[m][r] = 0.f;
    #pragma unroll
    for (int n = 0; n < 4; n++) {
        int d = wv * 128 + n * 32 + l31;
        float pd  = proj[b * 1024 + d];
        float vv  = V[d];
        float vv2 = 2.f * vv;
        #pragma unroll
        for (int m = 0; m < 2; m++)
            #pragma unroll
            for (int r = 0; r < 16; r++) {
                float y  = acc[m][n][r] + pd;
                float e2 = __expf(2.f * y);                 // saturates at +/-inf
                float rc = __builtin_amdgcn_rcpf(e2 + 1.f);
                sc[m][r] += vv - vv2 * rc;                  // vv * tanh(y)
            }
    }

    // butterfly sum over the 32-lane column group (halves independent)
    #pragma unroll
    for (int m = 0; m < 2; m++)
        #pragma unroll
        for (int r = 0; r < 16; r++) {
            float v = sc[m][r];
            v += __shfl_xor(v, 1, 64);
            v += __shfl_xor(v, 2, 64);
            v += __shfl_xor(v, 4, 64);
            v += __shfl_xor(v, 8, 64);
            v += __shfl_xor(v, 16, 64);
            sc[m][r] = v;
        }

    __syncthreads();           // all waves done with LDS; safe to alias
    float* redf = (float*)SM;                  // [64 tok][8 wv] f32 = 2KB
    float* pf   = (float*)SM + 512;            // 64 f32: p per slot
    int*   ri   = (int*)SM + 576;              // 64 ints: local row per slot
    if (l31 == 0) {
        #pragma unroll
        for (int m = 0; m < 2; m++)
            #pragma unroll
            for (int r = 0; r < 16; r++) {
                int tok = m * 32 + (r & 3) + 8 * (r >> 2) + 4 * hi;
                redf[tok * 8 + wv] = sc[m][r];
            }
    }
    __syncthreads();
    if (tid < 64) {
        float s = 0.f;
        #pragma unroll
        for (int w = 0; w < 8; w++) s += redf[tid * 8 + w];
        int sidx = idx[b * SS + lt0 + tid];
        float p = (sidx >= 0) ? __expf(s) : 0.f;   // shift-free softmax: |s|<=51
        if (sidx >= 0) psc[b * SS + sidx] = p;
        pf[tid] = p;
        ri[tid] = sidx & 2047;                     // sentinel -> row 0 (p=0)
        float z = p;
        z += __shfl_xor(z, 1, 64);
        z += __shfl_xor(z, 2, 64);
        z += __shfl_xor(z, 4, 64);
        z += __shfl_xor(z, 8, 64);
        z += __shfl_xor(z, 16, 64);
        z += __shfl_xor(z, 32, 64);
        if (tid == 0) pZ[b * 32 + loc] = z;
    }
    __syncthreads();

    // ---- fused PV: N[e] = sum_s p_s * enc[row_s][e], branch-free, MLP=16 ----
    float n0 = 0.f, n1 = 0.f;
    const float* encb = enc + (size_t)b * SS * 1024;
    #pragma unroll 8
    for (int s2 = 0; s2 < 64; s2++) {
        float p = pf[s2];
        const float* rp = encb + (size_t)ri[s2] * 1024;
        n0 = fmaf(p, rp[tid], n0);
        n1 = fmaf(p, rp[tid + 512], n1);
    }
    float* pn = pnum + (size_t)(b * 32 + loc) * 1024;
    pn[tid]       = n0;
    pn[tid + 512] = n1;
}

// ---------------- finish: ctx finalize (bx<128) | attn normalize (bx>=128) ---
__global__ __launch_bounds__(256) void k_finish(const float* __restrict__ pnum,
                                                const float* __restrict__ psc,
                                                const int* __restrict__ mask,
                                                const float* __restrict__ pZ,
                                                const int* __restrict__ cntblk,
                                                float* __restrict__ ctx,
                                                float* __restrict__ attn) {
    const int bx = blockIdx.x, tid = threadIdx.x;
    if (bx < 128) {
        // ---- ctx = (sum partial N) / Z ----
        int i = bx * 256 + tid;                   // 0..32767
        int b = i >> 10, e = i & 1023;
        const int c = cntblk[b];
        float Z = 0.f;
        for (int q = 0; q < c; q++) Z += pZ[b * 32 + q];
        float s = 0.f;
        for (int q = 0; q < c; q++) s += pnum[(size_t)(b * 32 + q) * 1024 + e];
        ctx[i] = s / Z;
    } else {
        // ---- attn = mask ? 0 : p/Z ----
        const int b = bx - 128;
        const int c = cntblk[b];
        float Z = 0.f;
        for (int q = 0; q < c; q++) Z += pZ[b * 32 + q];
        float invZ = 1.f / Z;
        #pragma unroll
        for (int i = 0; i < 8; i++) {
            int s = tid + i * 256;
            int m = mask[b * SS + s];
            float p = m ? 0.f : psc[b * SS + s];
            attn[b * SS + s] = p * invZ;
        }
    }
}

// ================= fp32 fallback (round-0 proven path) =================
__global__ __launch_bounds__(256) void k_projdec2(const float* __restrict__ dec,
                                                  const float* __restrict__ W,
                                                  float* __restrict__ proj) {
    const int tid = threadIdx.x;
    const int dl = tid >> 6;
    const int b  = (tid >> 1) & 31;
    const int hf = tid & 1;
    const int d  = blockIdx.x * 4 + dl;
    const float* wrow = W + (size_t)d * WROW + HE + hf * 512;
    const float* dv   = dec + b * HD + hf * 512;
    float s = 0.f;
    #pragma unroll 4
    for (int e = 0; e < 512; e += 4) {
        float4 w4 = *(const float4*)(wrow + e);
        float4 x4 = *(const float4*)(dv + e);
        s += w4.x * x4.x + w4.y * x4.y + w4.z * x4.z + w4.w * x4.w;
    }
    s += __shfl_xor(s, 1, 64);
    if (hf == 0) proj[b * HD + d] = s;
}

__global__ __launch_bounds__(256) void k_scores_f32(const float* __restrict__ enc,
                                                    const float* __restrict__ W,
                                                    const float* __restrict__ V,
                                                    const float* __restrict__ proj,
                                                    float* __restrict__ scores) {
    __shared__ float As[64][20];
    __shared__ float Bs[64][20];
    __shared__ float red[64][17];
    const int t0 = blockIdx.x * 64;
    const int b  = t0 >> 11;
    const int tid = threadIdx.x;
    const int tx = tid & 15, ty = tid >> 4;
    const int lrow = tid >> 2, lc4 = (tid & 3) * 4;
    float sc[4] = {0.f, 0.f, 0.f, 0.f};
    for (int n0 = 0; n0 < HD; n0 += 64) {
        float C[4][4] = {};
        for (int k0 = 0; k0 < HE; k0 += 16) {
            *(float4*)&As[lrow][lc4] = *(const float4*)(enc + (size_t)(t0 + lrow) * HE + k0 + lc4);
            *(float4*)&Bs[lrow][lc4] = *(const float4*)(W + (size_t)(n0 + lrow) * WROW + k0 + lc4);
            __syncthreads();
            #pragma unroll
            for (int k4 = 0; k4 < 16; k4 += 4) {
                float4 a[4], bb[4];
                #pragma unroll
                for (int i = 0; i < 4; i++) a[i]  = *(float4*)&As[ty * 4 + i][k4];
                #pragma unroll
                for (int j = 0; j < 4; j++) bb[j] = *(float4*)&Bs[tx * 4 + j][k4];
                #pragma unroll
                for (int i = 0; i < 4; i++)
                    #pragma unroll
                    for (int j = 0; j < 4; j++)
                        C[i][j] += a[i].x * bb[j].x + a[i].y * bb[j].y +
                                   a[i].z * bb[j].z + a[i].w * bb[j].w;
            }
            __syncthreads();
        }
        #pragma unroll
        for (int j = 0; j < 4; j++) {
            int d = n0 + tx * 4 + j;
            float pd = proj[b * HD + d];
            float v  = V[d];
            #pragma unroll
            for (int i = 0; i < 4; i++) {
                float y  = C[i][j] + pd;
                float e2 = __expf(2.f * y);
                sc[i] += v * (1.f - 2.f / (e2 + 1.f));
            }
        }
    }
    #pragma unroll
    for (int i = 0; i < 4; i++) red[ty * 4 + i][tx] = sc[i];
    __syncthreads();
    if (tid < 64) {
        float s = 0.f;
        #pragma unroll
        for (int x = 0; x < 16; x++) s += red[tid][x];
        scores[t0 + tid] = s;
    }
}

__global__ __launch_bounds__(256) void k_softmax_f32(float* __restrict__ sc_attn,
                                                     const int* __restrict__ mask) {
    __shared__ float sred[256];
    const int b = blockIdx.x, tid = threadIdx.x;
    float vals[8]; int msk[8];
    float lmax = -1e30f;
    #pragma unroll
    for (int i = 0; i < 8; i++) {
        int s = tid + i * 256;
        vals[i] = sc_attn[b * SS + s];
        msk[i]  = mask[b * SS + s];
        if (!msk[i]) lmax = fmaxf(lmax, vals[i]);
    }
    sred[tid] = lmax; __syncthreads();
    for (int off = 128; off > 0; off >>= 1) {
        if (tid < off) sred[tid] = fmaxf(sred[tid], sred[tid + off]);
        __syncthreads();
    }
    float m = sred[0];
    __syncthreads();
    float ex[8]; float lsum = 0.f;
    #pragma unroll
    for (int i = 0; i < 8; i++) { ex[i] = msk[i] ? 0.f : __expf(vals[i] - m); lsum += ex[i]; }
    sred[tid] = lsum; __syncthreads();
    for (int off = 128; off > 0; off >>= 1) {
        if (tid < off) sred[tid] += sred[tid + off];
        __syncthreads();
    }
    float inv = 1.f / sred[0];
    #pragma unroll
    for (int i = 0; i < 8; i++) sc_attn[b * SS + tid + i * 256] = ex[i] * inv;
}

__global__ __launch_bounds__(256) void k_ctx_atomic(const float* __restrict__ enc,
                                                    const float* __restrict__ attn,
                                                    float* __restrict__ ctx) {
    const int b = blockIdx.x;
    const int e = blockIdx.y * 256 + threadIdx.x;
    const int s0 = blockIdx.z * 256;
    float sum = 0.f;
    for (int s = s0; s < s0 + 256; s++)
        sum += attn[b * SS + s] * enc[((size_t)b * SS + s) * HE + e];
    atomicAdd(&ctx[b * HE + e], sum);
}

extern "C" void kernel_launch(void* const* d_in, const int* in_sizes, int n_in,
                              void* d_out, int out_size, void* d_ws, size_t ws_size,
                              hipStream_t stream) {
    const float* enc  = (const float*)d_in[0];
    const float* dec  = (const float*)d_in[1];
    const int*   mask = (const int*)d_in[2];
    const float* W    = (const float*)d_in[3];
    const float* V    = (const float*)d_in[4];

    float* out  = (float*)d_out;
    float* ctx  = out;               // [32][1024]
    float* attn = out + BB * HE;     // [32][2048]

    // ws layout (bytes): wf 2M | proj 128K | psc 256K | idx 256K | cnt 4K | pZ 4K | pnum 4M
    const size_t WF_OFF = 0, PROJ_OFF = 2097152, PSC_OFF = PROJ_OFF + 131072,
                 IDX_OFF = PSC_OFF + 262144, CNT_OFF = IDX_OFF + 262144,
                 PZ_OFF = CNT_OFF + 4096, PN_OFF = PZ_OFF + 4096,
                 WS_NEED = PN_OFF + 4194304;
    if (ws_size >= WS_NEED) {
        char* w = (char*)d_ws;
        unsigned short* wf = (unsigned short*)(w + WF_OFF);
        float* proj        = (float*)(w + PROJ_OFF);
        float* psc         = (float*)(w + PSC_OFF);
        int*   idx         = (int*)(w + IDX_OFF);
        int*   cntblk      = (int*)(w + CNT_OFF);
        float* pZ          = (float*)(w + PZ_OFF);
        float* pnum        = (float*)(w + PN_OFF);

        k_prep<<<800, 256, 0, stream>>>(W, dec, mask, wf, proj, idx, cntblk);
        k_scores_mfma8b<<<1024, 512, 0, stream>>>(enc, wf, V, proj, idx, cntblk,
                                                  psc, pZ, pnum);
        k_finish<<<160, 256, 0, stream>>>(pnum, psc, mask, pZ, cntblk, ctx, attn);
    } else {
        float* proj  = ctx;
        float* score = attn;
        k_projdec2<<<256, 256, 0, stream>>>(dec, W, proj);
        k_scores_f32<<<(BB * SS) / 64, 256, 0, stream>>>(enc, W, V, proj, score);
        k_softmax_f32<<<BB, 256, 0, stream>>>(score, mask);
        hipMemsetAsync(ctx, 0, (size_t)BB * HE * sizeof(float), stream);
        k_ctx_atomic<<<dim3(BB, HE / 256, 8), 256, 0, stream>>>(enc, attn, ctx);
    }
}